// Round 10
// baseline (291.349 us; speedup 1.0000x reference)
//
#include <hip/hip_runtime.h>
#include <math.h>

#define SCALE 0.36067376022224085f  // 0.25 * log2(e): folded attn scale for exp2-domain softmax

// ws float offsets
#define WVF1F 0      // [32][64] folded ip_w2@wv (layer1)
#define WVF2F 2048   // [32][64] layer2
#define WKT2F 4096   // [64][32] transposed folded ip_w2@wk2 * SCALE (legacy)
#define G1F   6144   // [12][32] g1 (layer-1 score weights)
#define BVF1F 6528   // [64] folded v bias layer1
#define BVF2F 6592   // [64] layer2
// packed float4 weight layouts: P*[jc*4d_stride + d*4 + r] = W[(jc*4+r)*D + d]
#define PQ2   6656
#define PO1   10752
#define PO2   14848
#define PV1   18944
#define PV2   20992
#define PF1   23040
#define PF2   31232
#define POP1  39424
#define PKT2F 41472  // [32j][64D] SCALE * Wkf2 row-major

#define WSYNC() do { asm volatile("s_waitcnt lgkmcnt(0)" ::: "memory"); __builtin_amdgcn_wave_barrier(); } while (0)

struct Params {
  const float* tl; const float* tr; const float* qemb;
  const float* ip_w1; const float* ip_b1;
  const float* bq2;
  const float* bo1; const float* bo2;
  const float* ffn_b1; const float* ffn_b2;
  const float* n1_g; const float* n1_b;
  const float* n2_g; const float* n2_b;
  const float* n3_g; const float* n3_b;
  const float* op_b1;
  const float* op_w2; const float* op_b2;
  const float* ws;
  float* out;
};

__global__ void prep1_kernel(const float* ip_w2, const float* ip_b2,
                             const float* wk2, const float* wv1, const float* wv2,
                             const float* bv1, const float* bv2, float* ws) {
  const int bid = blockIdx.x, tid = threadIdx.x;
  if (bid < 24) {
    const int idx = bid * 256 + tid;
    const int mat = idx >> 11;
    const int rem = idx & 2047;
    const int j = rem >> 6, c = rem & 63;
    const float* W = (mat == 0) ? wv1 : (mat == 1) ? wv2 : wk2;
    float acc = 0.f;
    for (int m = 0; m < 64; ++m) acc = fmaf(ip_w2[j * 64 + m], W[m * 64 + c], acc);
    if (mat == 0)      ws[WVF1F + j * 64 + c] = acc;
    else if (mat == 1) ws[WVF2F + j * 64 + c] = acc;
    else {
      ws[WKT2F + c * 32 + j] = acc * SCALE;
      ws[PKT2F + j * 64 + c] = acc * SCALE;
    }
  } else if (tid < 128) {
    const int l = tid >> 6, d = tid & 63;
    const float* bv = l ? bv2 : bv1;
    const float* wv = l ? wv2 : wv1;
    float acc = bv[d];
    for (int m = 0; m < 64; ++m) acc = fmaf(ip_b2[m], wv[m * 64 + d], acc);
    ws[(l ? BVF2F : BVF1F) + d] = acc;
  }
}

__global__ void prep2_kernel(const float* ip_w2, const float* wk1,
                             const float* qemb, const float* wq1, const float* bq1,
                             float* ws) {
  __shared__ float wkf[32][64];
  __shared__ float q1[3][64];
  const int tid = threadIdx.x;   // 384
  for (int e = tid; e < 2048; e += 384) {
    const int j = e >> 6, c = e & 63;
    float acc = 0.f;
    for (int m = 0; m < 64; ++m) acc = fmaf(ip_w2[j * 64 + m], wk1[m * 64 + c], acc);
    wkf[j][c] = acc;
  }
  if (tid < 192) {
    const int q = tid >> 6, d = tid & 63;
    float acc = bq1[d];
    for (int e = 0; e < 64; ++e) acc = fmaf(qemb[q * 64 + e], wq1[e * 64 + d], acc);
    q1[q][d] = acc;
  }
  __syncthreads();
  {
    const int r = tid >> 5, j = tid & 31;
    const int h = r / 3, q = r - h * 3;
    float acc = 0.f;
    for (int d = 0; d < 16; ++d) acc = fmaf(wkf[j][h * 16 + d], q1[q][h * 16 + d], acc);
    ws[G1F + r * 32 + j] = acc * SCALE;
  }
}

__global__ void prepC_kernel(float* ws,
                             const float* wq2, const float* wo1, const float* wo2,
                             const float* fw1, const float* fw2, const float* opw1) {
  const int e = blockIdx.x * 256 + threadIdx.x;
  if (e >= 34816) return;
  float v; int dst;
  if (e < 4096) {
    const int i = e, jc = i >> 8, rem = i & 255, d = rem >> 2, r = rem & 3;
    v = wq2[(jc * 4 + r) * 64 + d]; dst = PQ2 + i;
  } else if (e < 8192) {
    const int i = e - 4096, jc = i >> 8, rem = i & 255, d = rem >> 2, r = rem & 3;
    v = wo1[(jc * 4 + r) * 64 + d]; dst = PO1 + i;
  } else if (e < 12288) {
    const int i = e - 8192, jc = i >> 8, rem = i & 255, d = rem >> 2, r = rem & 3;
    v = wo2[(jc * 4 + r) * 64 + d]; dst = PO2 + i;
  } else if (e < 14336) {
    const int i = e - 12288, jc = i >> 8, rem = i & 255, d = rem >> 2, r = rem & 3;
    v = ws[WVF1F + (jc * 4 + r) * 64 + d]; dst = PV1 + i;
  } else if (e < 16384) {
    const int i = e - 14336, jc = i >> 8, rem = i & 255, d = rem >> 2, r = rem & 3;
    v = ws[WVF2F + (jc * 4 + r) * 64 + d]; dst = PV2 + i;
  } else if (e < 24576) {
    const int i = e - 16384, jc = i >> 9, rem = i & 511, d = rem >> 2, r = rem & 3;
    v = fw1[(jc * 4 + r) * 128 + d]; dst = PF1 + i;
  } else if (e < 32768) {
    const int i = e - 24576, mc = i >> 8, rem = i & 255, d = rem >> 2, r = rem & 3;
    v = fw2[(mc * 4 + r) * 64 + d]; dst = PF2 + i;
  } else {
    const int i = e - 32768, jc = i >> 7, rem = i & 127, d = rem >> 2, r = rem & 3;
    v = opw1[(jc * 4 + r) * 32 + d]; dst = POP1 + i;
  }
  ws[dst] = v;
}

// 2-wave blocks, 1 item/wave, LDS diet: 14.2KB/block -> ~11 blocks = 22 waves/CU
// (R6 was 20). Waves fully independent (g1 read from global; no __syncthreads).
__global__ __launch_bounds__(128) void planner_kernel(Params p) {
  const int w = threadIdx.x >> 6;
  const int lane = threadIdx.x & 63;
  const int item = blockIdx.x * 2 + w;

  __shared__ __align__(16) float a_s[2][20][36];     // acts; later f1 overlay [3][136]
  __shared__ __align__(16) float att_s[2][12][20];   // pts staging -> scores -> probs
  __shared__ __align__(16) float ch_s[2][12][36];    // att@a; also g2
  __shared__ __align__(16) float qx_s[2][3][64];     // q2 / o / y1
  __shared__ __align__(16) float x_s[2][3][64];      // residual stream

  const float* ws = p.ws;

  // stage points into att-overlay (dead before scores write att)
  float* pts = (float*)att_s[w];
  if (lane < 40)
    pts[lane] = (lane < 20) ? p.tl[item * 20 + lane] : p.tr[item * 20 + lane - 20];
  WSYNC();

  // a = relu(pts @ ip_w1 + ip_b1)   [20][32]
  {
    const int j = lane & 31, th = lane >> 5;
    const float w0 = p.ip_w1[j], w1 = p.ip_w1[32 + j], b = p.ip_b1[j];
#pragma unroll
    for (int i = 0; i < 10; ++i) {
      const int t = th * 10 + i;
      a_s[w][t][j] = fmaxf(fmaf(pts[2 * t], w0, fmaf(pts[2 * t + 1], w1, b)), 0.f);
    }
  }
  WSYNC();

  const int t3 = lane / 3;
  const int q3 = lane - t3 * 3;
  const int j32 = lane & 31, half = lane >> 5, hq0 = half * 6;
  const int h16 = lane >> 4;
  const int r12 = lane >> 2, sub = lane & 3;   // parallel softmax mapping

  float xq[3];

#pragma unroll
  for (int l = 0; l < 2; ++l) {
    if (l == 1) {
      // Q2 projection: lane = channel, packed float4 weights
      float acc[3];
#pragma unroll
      for (int q = 0; q < 3; ++q) acc[q] = p.bq2[lane];
#pragma unroll
      for (int jc = 0; jc < 16; ++jc) {
        const float4 w4 = *(const float4*)&ws[PQ2 + jc * 256 + lane * 4];
#pragma unroll
        for (int q = 0; q < 3; ++q) {
          const float4 xv = *(const float4*)&x_s[w][q][jc * 4];
          acc[q] = fmaf(xv.x, w4.x, fmaf(xv.y, w4.y, fmaf(xv.z, w4.z, fmaf(xv.w, w4.w, acc[q]))));
        }
      }
#pragma unroll
      for (int q = 0; q < 3; ++q) qx_s[w][q][lane] = acc[q];
      WSYNC();
      // g2[hl*3+q][j] = sum_D PKT[j][D] * q2[q][D]  (float4 packed; SCALE folded)
      {
        float g2[6] = {0, 0, 0, 0, 0, 0};
        const int D0 = half * 32;
        const float* pkt = &ws[PKT2F + j32 * 64 + D0];
#pragma unroll
        for (int dd = 0; dd < 8; ++dd) {
          const float4 wk4 = *(const float4*)&pkt[dd * 4];
          const int hl = dd >> 2;
#pragma unroll
          for (int q = 0; q < 3; ++q) {
            const float4 q4 = *(const float4*)&qx_s[w][q][D0 + dd * 4];
            g2[hl * 3 + q] = fmaf(q4.x, wk4.x, fmaf(q4.y, wk4.y,
                              fmaf(q4.z, wk4.z, fmaf(q4.w, wk4.w, g2[hl * 3 + q]))));
          }
        }
#pragma unroll
        for (int k = 0; k < 6; ++k) ch_s[w][hq0 + k][j32] = g2[k];
      }
      WSYNC();
    }

    // scores: lane=(t,q), s[h] = sum_j a[t][j] * g[h*3+q][j]
    if (lane < 60) {
      float acc[4] = {0, 0, 0, 0};
      if (l == 0) {
        // g1 from global (L1-resident 1.5KB)
#pragma unroll
        for (int jc = 0; jc < 8; ++jc) {
          const float4 av = *(const float4*)&a_s[w][t3][jc * 4];
#pragma unroll
          for (int h = 0; h < 4; ++h) {
            const float4 gv = *(const float4*)&ws[G1F + (h * 3 + q3) * 32 + jc * 4];
            acc[h] = fmaf(av.x, gv.x, fmaf(av.y, gv.y, fmaf(av.z, gv.z, fmaf(av.w, gv.w, acc[h]))));
          }
        }
      } else {
#pragma unroll
        for (int jc = 0; jc < 8; ++jc) {
          const float4 av = *(const float4*)&a_s[w][t3][jc * 4];
#pragma unroll
          for (int h = 0; h < 4; ++h) {
            const float4 gv = *(const float4*)&ch_s[w][h * 3 + q3][jc * 4];
            acc[h] = fmaf(av.x, gv.x, fmaf(av.y, gv.y, fmaf(av.z, gv.z, fmaf(av.w, gv.w, acc[h]))));
          }
        }
      }
#pragma unroll
      for (int h = 0; h < 4; ++h) att_s[w][h * 3 + q3][t3] = acc[h];
    }
    WSYNC();

    // wave-parallel softmax: 4 lanes/row x 5 t each; writes normalized probs
    if (r12 < 12) {
      const int tb = sub * 5;
      float v0 = att_s[w][r12][tb],     v1 = att_s[w][r12][tb + 1];
      float v2 = att_s[w][r12][tb + 2], v3 = att_s[w][r12][tb + 3];
      float v4 = att_s[w][r12][tb + 4];
      float m = fmaxf(fmaxf(fmaxf(v0, v1), fmaxf(v2, v3)), v4);
      m = fmaxf(m, __shfl_xor(m, 1));
      m = fmaxf(m, __shfl_xor(m, 2));
      v0 = exp2f(v0 - m); v1 = exp2f(v1 - m); v2 = exp2f(v2 - m);
      v3 = exp2f(v3 - m); v4 = exp2f(v4 - m);
      float s = v0 + v1 + v2 + v3 + v4;
      s += __shfl_xor(s, 1);
      s += __shfl_xor(s, 2);
      const float inv = 1.f / s;
      att_s[w][r12][tb]     = v0 * inv;
      att_s[w][r12][tb + 1] = v1 * inv;
      att_s[w][r12][tb + 2] = v2 * inv;
      att_s[w][r12][tb + 3] = v3 * inv;
      att_s[w][r12][tb + 4] = v4 * inv;
    }
    WSYNC();

    // ch[hq][j] = sum_t att[hq][t] * a[t][j]  (att normalized)
    {
      float c[6] = {0, 0, 0, 0, 0, 0};
#pragma unroll
      for (int tc = 0; tc < 5; ++tc) {
        float av[4];
#pragma unroll
        for (int r = 0; r < 4; ++r) av[r] = a_s[w][tc * 4 + r][j32];
#pragma unroll
        for (int k = 0; k < 6; ++k) {
          const float4 at = *(const float4*)&att_s[w][hq0 + k][tc * 4];
          c[k] = fmaf(at.x, av[0], fmaf(at.y, av[1], fmaf(at.z, av[2], fmaf(at.w, av[3], c[k]))));
        }
      }
#pragma unroll
      for (int k = 0; k < 6; ++k) ch_s[w][hq0 + k][j32] = c[k];
    }
    WSYNC();

    // o[q][d] = sum_j ch[h(d)*3+q][j] * Wvf[j][d] + bvf[d]  (packed Wv)
    {
      const int pv = l ? PV2 : PV1;
      const float bv = ws[(l ? BVF2F : BVF1F) + lane];
      float o[3] = {bv, bv, bv};
#pragma unroll
      for (int jc = 0; jc < 8; ++jc) {
        const float4 w4 = *(const float4*)&ws[pv + jc * 256 + lane * 4];
#pragma unroll
        for (int q = 0; q < 3; ++q) {
          const float4 cv = *(const float4*)&ch_s[w][h16 * 3 + q][jc * 4];
          o[q] = fmaf(cv.x, w4.x, fmaf(cv.y, w4.y, fmaf(cv.z, w4.z, fmaf(cv.w, w4.w, o[q]))));
        }
      }
#pragma unroll
      for (int q = 0; q < 3; ++q) qx_s[w][q][lane] = o[q];
    }
    WSYNC();

    // O-proj + residual + LN  (packed wo)
    {
      const int po = l ? PO2 : PO1;
      const float* bo = l ? p.bo2 : p.bo1;
      const float* gg = l ? p.n2_g : p.n1_g;
      const float* gb = l ? p.n2_b : p.n1_b;
      float acc[3];
#pragma unroll
      for (int q = 0; q < 3; ++q)
        acc[q] = bo[lane] + (l ? xq[q] : p.qemb[q * 64 + lane]);
#pragma unroll
      for (int jc = 0; jc < 16; ++jc) {
        const float4 w4 = *(const float4*)&ws[po + jc * 256 + lane * 4];
#pragma unroll
        for (int q = 0; q < 3; ++q) {
          const float4 ov = *(const float4*)&qx_s[w][q][jc * 4];
          acc[q] = fmaf(ov.x, w4.x, fmaf(ov.y, w4.y, fmaf(ov.z, w4.z, fmaf(ov.w, w4.w, acc[q]))));
        }
      }
      const float gv = gg[lane], bv = gb[lane];
#pragma unroll
      for (int q = 0; q < 3; ++q) {
        const float v = acc[q];
        float s = v;
#pragma unroll
        for (int m = 32; m >= 1; m >>= 1) s += __shfl_xor(s, m);
        const float mu = s * (1.f / 64.f);
        const float d = v - mu;
        float s2 = d * d;
#pragma unroll
        for (int m = 32; m >= 1; m >>= 1) s2 += __shfl_xor(s2, m);
        const float inv = rsqrtf(s2 * (1.f / 64.f) + 1e-5f);
        const float xn = fmaf(d * inv, gv, bv);
        xq[q] = xn;
        x_s[w][q][lane] = xn;
      }
    }
    WSYNC();
  }

  // FFN1: f1 = relu(x2 @ w1 + b1) -> overlay on a_s
  float* f1p = (float*)a_s[w];
  {
    float a0[3], a1[3];
    const float b0 = p.ffn_b1[lane], b1 = p.ffn_b1[64 + lane];
#pragma unroll
    for (int q = 0; q < 3; ++q) { a0[q] = b0; a1[q] = b1; }
#pragma unroll
    for (int jc = 0; jc < 16; ++jc) {
      const float4 w04 = *(const float4*)&ws[PF1 + jc * 512 + lane * 4];
      const float4 w14 = *(const float4*)&ws[PF1 + jc * 512 + 256 + lane * 4];
#pragma unroll
      for (int q = 0; q < 3; ++q) {
        const float4 xv = *(const float4*)&x_s[w][q][jc * 4];
        a0[q] = fmaf(xv.x, w04.x, fmaf(xv.y, w04.y, fmaf(xv.z, w04.z, fmaf(xv.w, w04.w, a0[q]))));
        a1[q] = fmaf(xv.x, w14.x, fmaf(xv.y, w14.y, fmaf(xv.z, w14.z, fmaf(xv.w, w14.w, a1[q]))));
      }
    }
#pragma unroll
    for (int q = 0; q < 3; ++q) {
      f1p[q * 136 + lane] = fmaxf(a0[q], 0.f);
      f1p[q * 136 + 64 + lane] = fmaxf(a1[q], 0.f);
    }
  }
  WSYNC();

  // FFN2 + residual + LN3
  {
    float acc[3];
#pragma unroll
    for (int q = 0; q < 3; ++q) acc[q] = p.ffn_b2[lane] + xq[q];
#pragma unroll
    for (int mc = 0; mc < 32; ++mc) {
      const float4 w4 = *(const float4*)&ws[PF2 + mc * 256 + lane * 4];
#pragma unroll
      for (int q = 0; q < 3; ++q) {
        const float4 fv = *(const float4*)&f1p[q * 136 + mc * 4];
        acc[q] = fmaf(fv.x, w4.x, fmaf(fv.y, w4.y, fmaf(fv.z, w4.z, fmaf(fv.w, w4.w, acc[q]))));
      }
    }
    const float gv = p.n3_g[lane], bv = p.n3_b[lane];
#pragma unroll
    for (int q = 0; q < 3; ++q) {
      const float v = acc[q];
      float s = v;
#pragma unroll
      for (int m = 32; m >= 1; m >>= 1) s += __shfl_xor(s, m);
      const float mu = s * (1.f / 64.f);
      const float d = v - mu;
      float s2 = d * d;
#pragma unroll
      for (int m = 32; m >= 1; m >>= 1) s2 += __shfl_xor(s2, m);
      const float inv = rsqrtf(s2 * (1.f / 64.f) + 1e-5f);
      x_s[w][q][lane] = fmaf(d * inv, gv, bv);
    }
  }
  WSYNC();

  // head 1: y1 = relu(x3 @ op_w1 + op_b1) [3][32]
  if (lane < 32) {
    float acc[3];
#pragma unroll
    for (int q = 0; q < 3; ++q) acc[q] = p.op_b1[lane];
#pragma unroll
    for (int jc = 0; jc < 16; ++jc) {
      const float4 w4 = *(const float4*)&ws[POP1 + jc * 128 + lane * 4];
#pragma unroll
      for (int q = 0; q < 3; ++q) {
        const float4 xv = *(const float4*)&x_s[w][q][jc * 4];
        acc[q] = fmaf(xv.x, w4.x, fmaf(xv.y, w4.y, fmaf(xv.z, w4.z, fmaf(xv.w, w4.w, acc[q]))));
      }
    }
#pragma unroll
    for (int q = 0; q < 3; ++q) qx_s[w][q][lane] = fmaxf(acc[q], 0.f);
  }
  WSYNC();

  // head 2: 24 lanes (q,e,mg), 8 m each + quad reduce
  if (lane < 24) {
    const int q = lane >> 3, e = (lane >> 2) & 1, mg = lane & 3;
    float acc = 0.f;
#pragma unroll
    for (int k = 0; k < 8; ++k) {
      const int m = mg * 8 + k;
      acc = fmaf(qx_s[w][q][m], p.op_w2[m * 2 + e], acc);
    }
    acc += __shfl_xor(acc, 1);
    acc += __shfl_xor(acc, 2);
    if (mg == 0)
      p.out[item * 6 + q * 2 + e] = acc + p.op_b2[e];
  }
}

extern "C" void kernel_launch(void* const* d_in, const int* in_sizes, int n_in,
                              void* d_out, int out_size, void* d_ws, size_t ws_size,
                              hipStream_t stream) {
  const float* in[40];
  for (int i = 0; i < n_in && i < 40; ++i) in[i] = (const float*)d_in[i];

  const float *a1_wq, *a1_wk, *a1_wv, *a1_wo, *a1_bq, *a1_bk, *a1_bv, *a1_bo;
  const float *a2_wq, *a2_wk, *a2_wv, *a2_wo, *a2_bq, *a2_bk, *a2_bv, *a2_bo;
  if (in_sizes[8] == 4096) {
    a1_wq = in[7];  a1_wk = in[8];  a1_wv = in[9];  a1_wo = in[10];
    a1_bq = in[11]; a1_bk = in[12]; a1_bv = in[13]; a1_bo = in[14];
    a2_wq = in[15]; a2_wk = in[16]; a2_wv = in[17]; a2_wo = in[18];
    a2_bq = in[19]; a2_bk = in[20]; a2_bv = in[21]; a2_bo = in[22];
  } else {
    a1_wq = in[7];  a1_bq = in[8];  a1_wk = in[9];  a1_bk = in[10];
    a1_wv = in[11]; a1_bv = in[12]; a1_wo = in[13]; a1_bo = in[14];
    a2_wq = in[15]; a2_bq = in[16]; a2_wk = in[17]; a2_bk = in[18];
    a2_wv = in[19]; a2_bv = in[20]; a2_wo = in[21]; a2_bo = in[22];
  }
  (void)a1_bk; (void)a2_bk;  // K biases fold out of softmax exactly

  float* ws = (float*)d_ws;
  prep1_kernel<<<25, 256, 0, stream>>>(in[5], in[6], a2_wk, a1_wv, a2_wv, a1_bv, a2_bv, ws);
  prep2_kernel<<<1, 384, 0, stream>>>(in[5], a1_wk, in[2], a1_wq, a1_bq, ws);
  prepC_kernel<<<136, 256, 0, stream>>>(ws, a2_wq, a1_wo, a2_wo, in[23], in[25], in[33]);

  Params p;
  p.tl = in[0]; p.tr = in[1]; p.qemb = in[2];
  p.ip_w1 = in[3]; p.ip_b1 = in[4];
  p.bq2 = a2_bq;
  p.bo1 = a1_bo; p.bo2 = a2_bo;
  p.ffn_b1 = in[24]; p.ffn_b2 = in[26];
  p.n1_g = in[27]; p.n1_b = in[28]; p.n2_g = in[29]; p.n2_b = in[30];
  p.n3_g = in[31]; p.n3_b = in[32];
  p.op_b1 = in[34]; p.op_w2 = in[35]; p.op_b2 = in[36];
  p.ws = ws; p.out = (float*)d_out;

  planner_kernel<<<16384, 128, 0, stream>>>(p);
}

// Round 11
// 240.048 us; speedup vs baseline: 1.2137x; 1.2137x over previous
//
#include <hip/hip_runtime.h>
#include <math.h>

#define SCALE 0.36067376022224085f  // 0.25 * log2(e): folded attn scale for exp2-domain softmax

// ws float offsets
#define WVF1F 0      // [32][64] folded ip_w2@wv (layer1)
#define WVF2F 2048   // [32][64] layer2
#define WKT2F 4096   // [64][32] transposed folded ip_w2@wk2 * SCALE (legacy)
#define G1F   6144   // [12][32] g1 (layer-1 score weights)
#define BVF1F 6528   // [64] folded v bias layer1
#define BVF2F 6592   // [64] layer2
// packed float4 weight layouts: P*[jc*4d_stride + d*4 + r] = W[(jc*4+r)*D + d]
#define PQ2   6656
#define PO1   10752
#define PO2   14848
#define PV1   18944
#define PV2   20992
#define PF1   23040
#define PF2   31232
#define POP1  39424
#define PKT2F 41472  // [32j][64D] SCALE * Wkf2 row-major (float4 g2 reads)

#define WSYNC() do { asm volatile("s_waitcnt lgkmcnt(0)" ::: "memory"); __builtin_amdgcn_wave_barrier(); } while (0)

struct Params {
  const float* tl; const float* tr; const float* qemb;
  const float* ip_w1; const float* ip_b1;
  const float* bq2;
  const float* bo1; const float* bo2;
  const float* ffn_b1; const float* ffn_b2;
  const float* n1_g; const float* n1_b;
  const float* n2_g; const float* n2_b;
  const float* n3_g; const float* n3_b;
  const float* op_b1;
  const float* op_w2; const float* op_b2;
  const float* ws;
  float* out;
};

__global__ void prep1_kernel(const float* ip_w2, const float* ip_b2,
                             const float* wk2, const float* wv1, const float* wv2,
                             const float* bv1, const float* bv2, float* ws) {
  const int bid = blockIdx.x, tid = threadIdx.x;
  if (bid < 24) {
    const int idx = bid * 256 + tid;
    const int mat = idx >> 11;
    const int rem = idx & 2047;
    const int j = rem >> 6, c = rem & 63;
    const float* W = (mat == 0) ? wv1 : (mat == 1) ? wv2 : wk2;
    float acc = 0.f;
    for (int m = 0; m < 64; ++m) acc = fmaf(ip_w2[j * 64 + m], W[m * 64 + c], acc);
    if (mat == 0)      ws[WVF1F + j * 64 + c] = acc;
    else if (mat == 1) ws[WVF2F + j * 64 + c] = acc;
    else {
      ws[WKT2F + c * 32 + j] = acc * SCALE;
      ws[PKT2F + j * 64 + c] = acc * SCALE;
    }
  } else if (tid < 128) {
    const int l = tid >> 6, d = tid & 63;
    const float* bv = l ? bv2 : bv1;
    const float* wv = l ? wv2 : wv1;
    float acc = bv[d];
    for (int m = 0; m < 64; ++m) acc = fmaf(ip_b2[m], wv[m * 64 + d], acc);
    ws[(l ? BVF2F : BVF1F) + d] = acc;
  }
}

__global__ void prep2_kernel(const float* ip_w2, const float* wk1,
                             const float* qemb, const float* wq1, const float* bq1,
                             float* ws) {
  __shared__ float wkf[32][64];
  __shared__ float q1[3][64];
  const int tid = threadIdx.x;   // 384
  for (int e = tid; e < 2048; e += 384) {
    const int j = e >> 6, c = e & 63;
    float acc = 0.f;
    for (int m = 0; m < 64; ++m) acc = fmaf(ip_w2[j * 64 + m], wk1[m * 64 + c], acc);
    wkf[j][c] = acc;
  }
  if (tid < 192) {
    const int q = tid >> 6, d = tid & 63;
    float acc = bq1[d];
    for (int e = 0; e < 64; ++e) acc = fmaf(qemb[q * 64 + e], wq1[e * 64 + d], acc);
    q1[q][d] = acc;
  }
  __syncthreads();
  {
    const int r = tid >> 5, j = tid & 31;
    const int h = r / 3, q = r - h * 3;
    float acc = 0.f;
    for (int d = 0; d < 16; ++d) acc = fmaf(wkf[j][h * 16 + d], q1[q][h * 16 + d], acc);
    ws[G1F + r * 32 + j] = acc * SCALE;
  }
}

__global__ void prepC_kernel(float* ws,
                             const float* wq2, const float* wo1, const float* wo2,
                             const float* fw1, const float* fw2, const float* opw1) {
  const int e = blockIdx.x * 256 + threadIdx.x;
  if (e >= 34816) return;
  float v; int dst;
  if (e < 4096) {
    const int i = e, jc = i >> 8, rem = i & 255, d = rem >> 2, r = rem & 3;
    v = wq2[(jc * 4 + r) * 64 + d]; dst = PQ2 + i;
  } else if (e < 8192) {
    const int i = e - 4096, jc = i >> 8, rem = i & 255, d = rem >> 2, r = rem & 3;
    v = wo1[(jc * 4 + r) * 64 + d]; dst = PO1 + i;
  } else if (e < 12288) {
    const int i = e - 8192, jc = i >> 8, rem = i & 255, d = rem >> 2, r = rem & 3;
    v = wo2[(jc * 4 + r) * 64 + d]; dst = PO2 + i;
  } else if (e < 14336) {
    const int i = e - 12288, jc = i >> 8, rem = i & 255, d = rem >> 2, r = rem & 3;
    v = ws[WVF1F + (jc * 4 + r) * 64 + d]; dst = PV1 + i;
  } else if (e < 16384) {
    const int i = e - 14336, jc = i >> 8, rem = i & 255, d = rem >> 2, r = rem & 3;
    v = ws[WVF2F + (jc * 4 + r) * 64 + d]; dst = PV2 + i;
  } else if (e < 24576) {
    const int i = e - 16384, jc = i >> 9, rem = i & 511, d = rem >> 2, r = rem & 3;
    v = fw1[(jc * 4 + r) * 128 + d]; dst = PF1 + i;
  } else if (e < 32768) {
    const int i = e - 24576, mc = i >> 8, rem = i & 255, d = rem >> 2, r = rem & 3;
    v = fw2[(mc * 4 + r) * 64 + d]; dst = PF2 + i;
  } else {
    const int i = e - 32768, jc = i >> 7, rem = i & 127, d = rem >> 2, r = rem & 3;
    v = opw1[(jc * 4 + r) * 32 + d]; dst = POP1 + i;
  }
  ws[dst] = v;
}

// R6 configuration (proven local optimum: 256-thr blocks, g1 in LDS, 1 item/wave,
// natural VGPR alloc, LDS 32KB -> 5 blocks/CU) + R8's register-neutral VALU cuts
// (wave-parallel softmax, packed-float4 g2, 24-lane head2). No prefetch registers.
__global__ __launch_bounds__(256) void planner_kernel(Params p) {
  const int w = threadIdx.x >> 6;
  const int lane = threadIdx.x & 63;
  const int item = blockIdx.x * 4 + w;

  __shared__ __align__(16) float g1_s[12][36];       // block-shared
  __shared__ __align__(16) float a_s[4][20][36];     // relu acts; later overlaid by f1[3][136]
  __shared__ __align__(16) float att_s[4][12][24];   // raw scores -> normalized probs
  __shared__ __align__(16) float ch_s[4][12][36];    // att@a; also holds g2
  __shared__ __align__(16) float qx_s[4][3][68];     // q2 / attn-out o / y1
  __shared__ __align__(16) float x_s[4][3][68];      // residual stream
  __shared__ float pts_s[4][40];

  const float* ws = p.ws;

  for (int e = threadIdx.x; e < 384; e += 256)
    g1_s[e >> 5][e & 31] = ws[G1F + e];

  if (lane < 40)
    pts_s[w][lane] = (lane < 20) ? p.tl[item * 20 + lane] : p.tr[item * 20 + lane - 20];
  WSYNC();

  // a = relu(pts @ ip_w1 + ip_b1)   [20][32]
  {
    const int j = lane & 31, th = lane >> 5;
    const float w0 = p.ip_w1[j], w1 = p.ip_w1[32 + j], b = p.ip_b1[j];
#pragma unroll
    for (int i = 0; i < 10; ++i) {
      const int t = th * 10 + i;
      a_s[w][t][j] = fmaxf(fmaf(pts_s[w][2 * t], w0, fmaf(pts_s[w][2 * t + 1], w1, b)), 0.f);
    }
  }
  __syncthreads();  // covers g1_s (cross-wave) and a_s

  const int t3 = lane / 3;
  const int q3 = lane - t3 * 3;
  const int j32 = lane & 31, half = lane >> 5, hq0 = half * 6;
  const int h16 = lane >> 4;
  const int r12 = lane >> 2, sub = lane & 3;   // parallel softmax mapping

  float xq[3];

#pragma unroll
  for (int l = 0; l < 2; ++l) {
    if (l == 1) {
      // Q2 projection: lane = channel, packed float4 weights
      float acc[3];
#pragma unroll
      for (int q = 0; q < 3; ++q) acc[q] = p.bq2[lane];
#pragma unroll
      for (int jc = 0; jc < 16; ++jc) {
        const float4 w4 = *(const float4*)&ws[PQ2 + jc * 256 + lane * 4];
#pragma unroll
        for (int q = 0; q < 3; ++q) {
          const float4 xv = *(const float4*)&x_s[w][q][jc * 4];
          acc[q] = fmaf(xv.x, w4.x, fmaf(xv.y, w4.y, fmaf(xv.z, w4.z, fmaf(xv.w, w4.w, acc[q]))));
        }
      }
#pragma unroll
      for (int q = 0; q < 3; ++q) qx_s[w][q][lane] = acc[q];
      WSYNC();
      // g2[hl*3+q][j] = sum_D PKT[j][D] * q2[q][D]  (float4 packed; SCALE folded)
      {
        float g2[6] = {0, 0, 0, 0, 0, 0};
        const int D0 = half * 32;
        const float* pkt = &ws[PKT2F + j32 * 64 + D0];
#pragma unroll
        for (int dd = 0; dd < 8; ++dd) {
          const float4 wk4 = *(const float4*)&pkt[dd * 4];
          const int hl = dd >> 2;
#pragma unroll
          for (int q = 0; q < 3; ++q) {
            const float4 q4 = *(const float4*)&qx_s[w][q][D0 + dd * 4];
            g2[hl * 3 + q] = fmaf(q4.x, wk4.x, fmaf(q4.y, wk4.y,
                              fmaf(q4.z, wk4.z, fmaf(q4.w, wk4.w, g2[hl * 3 + q]))));
          }
        }
#pragma unroll
        for (int k = 0; k < 6; ++k) ch_s[w][hq0 + k][j32] = g2[k];
      }
      WSYNC();
    }

    // scores: lane=(t,q), s[h] = sum_j a[t][j] * g[h*3+q][j]
    const float (*g)[36] = (l == 0) ? (const float (*)[36])g1_s : (const float (*)[36])ch_s[w];
    if (lane < 60) {
      float acc[4] = {0, 0, 0, 0};
#pragma unroll
      for (int jc = 0; jc < 8; ++jc) {
        const float4 av = *(const float4*)&a_s[w][t3][jc * 4];
#pragma unroll
        for (int h = 0; h < 4; ++h) {
          const float4 gv = *(const float4*)&g[h * 3 + q3][jc * 4];
          acc[h] = fmaf(av.x, gv.x, fmaf(av.y, gv.y, fmaf(av.z, gv.z, fmaf(av.w, gv.w, acc[h]))));
        }
      }
#pragma unroll
      for (int h = 0; h < 4; ++h) att_s[w][h * 3 + q3][t3] = acc[h];
    }
    WSYNC();

    // wave-parallel softmax: 4 lanes/row x 5 t each; writes normalized probs
    if (r12 < 12) {
      const int tb = sub * 5;
      float v0 = att_s[w][r12][tb],     v1 = att_s[w][r12][tb + 1];
      float v2 = att_s[w][r12][tb + 2], v3 = att_s[w][r12][tb + 3];
      float v4 = att_s[w][r12][tb + 4];
      float m = fmaxf(fmaxf(fmaxf(v0, v1), fmaxf(v2, v3)), v4);
      m = fmaxf(m, __shfl_xor(m, 1));
      m = fmaxf(m, __shfl_xor(m, 2));
      v0 = exp2f(v0 - m); v1 = exp2f(v1 - m); v2 = exp2f(v2 - m);
      v3 = exp2f(v3 - m); v4 = exp2f(v4 - m);
      float s = v0 + v1 + v2 + v3 + v4;
      s += __shfl_xor(s, 1);
      s += __shfl_xor(s, 2);
      const float inv = 1.f / s;
      att_s[w][r12][tb]     = v0 * inv;
      att_s[w][r12][tb + 1] = v1 * inv;
      att_s[w][r12][tb + 2] = v2 * inv;
      att_s[w][r12][tb + 3] = v3 * inv;
      att_s[w][r12][tb + 4] = v4 * inv;
    }
    WSYNC();

    // ch[hq][j] = sum_t att[hq][t] * a[t][j]  (att pre-normalized)
    {
      float c[6] = {0, 0, 0, 0, 0, 0};
#pragma unroll
      for (int tc = 0; tc < 5; ++tc) {
        float av[4];
#pragma unroll
        for (int r = 0; r < 4; ++r) av[r] = a_s[w][tc * 4 + r][j32];
#pragma unroll
        for (int k = 0; k < 6; ++k) {
          const float4 at = *(const float4*)&att_s[w][hq0 + k][tc * 4];
          c[k] = fmaf(at.x, av[0], fmaf(at.y, av[1], fmaf(at.z, av[2], fmaf(at.w, av[3], c[k]))));
        }
      }
#pragma unroll
      for (int k = 0; k < 6; ++k) ch_s[w][hq0 + k][j32] = c[k];
    }
    WSYNC();

    // o[q][d] = sum_j ch[h(d)*3+q][j] * Wvf[j][d] + bvf[d]  (packed Wv)
    {
      const int pv = l ? PV2 : PV1;
      const float bv = ws[(l ? BVF2F : BVF1F) + lane];
      float o[3] = {bv, bv, bv};
#pragma unroll
      for (int jc = 0; jc < 8; ++jc) {
        const float4 w4 = *(const float4*)&ws[pv + jc * 256 + lane * 4];
#pragma unroll
        for (int q = 0; q < 3; ++q) {
          const float4 cv = *(const float4*)&ch_s[w][h16 * 3 + q][jc * 4];
          o[q] = fmaf(cv.x, w4.x, fmaf(cv.y, w4.y, fmaf(cv.z, w4.z, fmaf(cv.w, w4.w, o[q]))));
        }
      }
#pragma unroll
      for (int q = 0; q < 3; ++q) qx_s[w][q][lane] = o[q];
    }
    WSYNC();

    // O-proj + residual + LN  (packed wo)
    {
      const int po = l ? PO2 : PO1;
      const float* bo = l ? p.bo2 : p.bo1;
      const float* gg = l ? p.n2_g : p.n1_g;
      const float* gb = l ? p.n2_b : p.n1_b;
      float acc[3];
#pragma unroll
      for (int q = 0; q < 3; ++q)
        acc[q] = bo[lane] + (l ? x_s[w][q][lane] : p.qemb[q * 64 + lane]);
#pragma unroll
      for (int jc = 0; jc < 16; ++jc) {
        const float4 w4 = *(const float4*)&ws[po + jc * 256 + lane * 4];
#pragma unroll
        for (int q = 0; q < 3; ++q) {
          const float4 ov = *(const float4*)&qx_s[w][q][jc * 4];
          acc[q] = fmaf(ov.x, w4.x, fmaf(ov.y, w4.y, fmaf(ov.z, w4.z, fmaf(ov.w, w4.w, acc[q]))));
        }
      }
      const float gv = gg[lane], bv = gb[lane];
#pragma unroll
      for (int q = 0; q < 3; ++q) {
        const float v = acc[q];
        float s = v;
#pragma unroll
        for (int m = 32; m >= 1; m >>= 1) s += __shfl_xor(s, m);
        const float mu = s * (1.f / 64.f);
        const float d = v - mu;
        float s2 = d * d;
#pragma unroll
        for (int m = 32; m >= 1; m >>= 1) s2 += __shfl_xor(s2, m);
        const float inv = rsqrtf(s2 * (1.f / 64.f) + 1e-5f);
        const float xn = fmaf(d * inv, gv, bv);
        xq[q] = xn;
        x_s[w][q][lane] = xn;
      }
    }
    WSYNC();
  }

  // FFN1: f1 = relu(x2 @ w1 + b1) -> overlay on a_s
  float* f1p = (float*)a_s[w];
  {
    float a0[3], a1[3];
    const float b0 = p.ffn_b1[lane], b1 = p.ffn_b1[64 + lane];
#pragma unroll
    for (int q = 0; q < 3; ++q) { a0[q] = b0; a1[q] = b1; }
#pragma unroll
    for (int jc = 0; jc < 16; ++jc) {
      const float4 w04 = *(const float4*)&ws[PF1 + jc * 512 + lane * 4];
      const float4 w14 = *(const float4*)&ws[PF1 + jc * 512 + 256 + lane * 4];
#pragma unroll
      for (int q = 0; q < 3; ++q) {
        const float4 xv = *(const float4*)&x_s[w][q][jc * 4];
        a0[q] = fmaf(xv.x, w04.x, fmaf(xv.y, w04.y, fmaf(xv.z, w04.z, fmaf(xv.w, w04.w, a0[q]))));
        a1[q] = fmaf(xv.x, w14.x, fmaf(xv.y, w14.y, fmaf(xv.z, w14.z, fmaf(xv.w, w14.w, a1[q]))));
      }
    }
#pragma unroll
    for (int q = 0; q < 3; ++q) {
      f1p[q * 136 + lane] = fmaxf(a0[q], 0.f);
      f1p[q * 136 + 64 + lane] = fmaxf(a1[q], 0.f);
    }
  }
  WSYNC();

  // FFN2 + residual + LN3
  {
    float acc[3];
#pragma unroll
    for (int q = 0; q < 3; ++q) acc[q] = p.ffn_b2[lane] + xq[q];
#pragma unroll
    for (int mc = 0; mc < 32; ++mc) {
      const float4 w4 = *(const float4*)&ws[PF2 + mc * 256 + lane * 4];
#pragma unroll
      for (int q = 0; q < 3; ++q) {
        const float4 fv = *(const float4*)&f1p[q * 136 + mc * 4];
        acc[q] = fmaf(fv.x, w4.x, fmaf(fv.y, w4.y, fmaf(fv.z, w4.z, fmaf(fv.w, w4.w, acc[q]))));
      }
    }
    const float gv = p.n3_g[lane], bv = p.n3_b[lane];
#pragma unroll
    for (int q = 0; q < 3; ++q) {
      const float v = acc[q];
      float s = v;
#pragma unroll
      for (int m = 32; m >= 1; m >>= 1) s += __shfl_xor(s, m);
      const float mu = s * (1.f / 64.f);
      const float d = v - mu;
      float s2 = d * d;
#pragma unroll
      for (int m = 32; m >= 1; m >>= 1) s2 += __shfl_xor(s2, m);
      const float inv = rsqrtf(s2 * (1.f / 64.f) + 1e-5f);
      x_s[w][q][lane] = fmaf(d * inv, gv, bv);
    }
  }
  WSYNC();

  // head 1: y1 = relu(x3 @ op_w1 + op_b1) [3][32]
  if (lane < 32) {
    float acc[3];
#pragma unroll
    for (int q = 0; q < 3; ++q) acc[q] = p.op_b1[lane];
#pragma unroll
    for (int jc = 0; jc < 16; ++jc) {
      const float4 w4 = *(const float4*)&ws[POP1 + jc * 128 + lane * 4];
#pragma unroll
      for (int q = 0; q < 3; ++q) {
        const float4 xv = *(const float4*)&x_s[w][q][jc * 4];
        acc[q] = fmaf(xv.x, w4.x, fmaf(xv.y, w4.y, fmaf(xv.z, w4.z, fmaf(xv.w, w4.w, acc[q]))));
      }
    }
#pragma unroll
    for (int q = 0; q < 3; ++q) qx_s[w][q][lane] = fmaxf(acc[q], 0.f);
  }
  WSYNC();

  // head 2: 24 lanes (q,e,mg), 8 m each + quad reduce
  if (lane < 24) {
    const int q = lane >> 3, e = (lane >> 2) & 1, mg = lane & 3;
    float acc = 0.f;
#pragma unroll
    for (int k = 0; k < 8; ++k) {
      const int m = mg * 8 + k;
      acc = fmaf(qx_s[w][q][m], p.op_w2[m * 2 + e], acc);
    }
    acc += __shfl_xor(acc, 1);
    acc += __shfl_xor(acc, 2);
    if (mg == 0)
      p.out[item * 6 + q * 2 + e] = acc + p.op_b2[e];
  }
}

extern "C" void kernel_launch(void* const* d_in, const int* in_sizes, int n_in,
                              void* d_out, int out_size, void* d_ws, size_t ws_size,
                              hipStream_t stream) {
  const float* in[40];
  for (int i = 0; i < n_in && i < 40; ++i) in[i] = (const float*)d_in[i];

  const float *a1_wq, *a1_wk, *a1_wv, *a1_wo, *a1_bq, *a1_bk, *a1_bv, *a1_bo;
  const float *a2_wq, *a2_wk, *a2_wv, *a2_wo, *a2_bq, *a2_bk, *a2_bv, *a2_bo;
  if (in_sizes[8] == 4096) {
    a1_wq = in[7];  a1_wk = in[8];  a1_wv = in[9];  a1_wo = in[10];
    a1_bq = in[11]; a1_bk = in[12]; a1_bv = in[13]; a1_bo = in[14];
    a2_wq = in[15]; a2_wk = in[16]; a2_wv = in[17]; a2_wo = in[18];
    a2_bq = in[19]; a2_bk = in[20]; a2_bv = in[21]; a2_bo = in[22];
  } else {
    a1_wq = in[7];  a1_bq = in[8];  a1_wk = in[9];  a1_bk = in[10];
    a1_wv = in[11]; a1_bv = in[12]; a1_wo = in[13]; a1_bo = in[14];
    a2_wq = in[15]; a2_bq = in[16]; a2_wk = in[17]; a2_bk = in[18];
    a2_wv = in[19]; a2_bv = in[20]; a2_wo = in[21]; a2_bo = in[22];
  }
  (void)a1_bk; (void)a2_bk;  // K biases fold out of softmax exactly

  float* ws = (float*)d_ws;
  prep1_kernel<<<25, 256, 0, stream>>>(in[5], in[6], a2_wk, a1_wv, a2_wv, a1_bv, a2_bv, ws);
  prep2_kernel<<<1, 384, 0, stream>>>(in[5], a1_wk, in[2], a1_wq, a1_bq, ws);
  prepC_kernel<<<136, 256, 0, stream>>>(ws, a2_wq, a1_wo, a2_wo, in[23], in[25], in[33]);

  Params p;
  p.tl = in[0]; p.tr = in[1]; p.qemb = in[2];
  p.ip_w1 = in[3]; p.ip_b1 = in[4];
  p.bq2 = a2_bq;
  p.bo1 = a1_bo; p.bo2 = a2_bo;
  p.ffn_b1 = in[24]; p.ffn_b2 = in[26];
  p.n1_g = in[27]; p.n1_b = in[28]; p.n2_g = in[29]; p.n2_b = in[30];
  p.n3_g = in[31]; p.n3_b = in[32];
  p.op_b1 = in[34]; p.op_w2 = in[35]; p.op_b2 = in[36];
  p.ws = ws; p.out = (float*)d_out;

  planner_kernel<<<8192, 256, 0, stream>>>(p);
}

// Round 12
// 235.542 us; speedup vs baseline: 1.2369x; 1.0191x over previous
//
#include <hip/hip_runtime.h>
#include <math.h>

#define SCALE 0.36067376022224085f  // 0.25 * log2(e): folded attn scale for exp2-domain softmax

// ws float offsets
#define WVF1F 0      // [32][64] folded ip_w2@wv (layer1)
#define WVF2F 2048   // [32][64] layer2
#define WKT2F 4096   // [64][32] transposed folded ip_w2@wk2 * SCALE (legacy)
#define G1F   6144   // [12][32] g1 (layer-1 score weights)
#define BVF1F 6528   // [64] folded v bias layer1
#define BVF2F 6592   // [64] layer2
// packed float4 weight layouts: P*[jc*4d_stride + d*4 + r] = W[(jc*4+r)*D + d]
#define PQ2   6656
#define PO1   10752
#define PO2   14848
#define PV1   18944
#define PV2   20992
#define PF1   23040
#define PF2   31232
#define POP1  39424
#define PKT2F 41472  // [32j][64D] SCALE * Wkf2 row-major (float4 g2 reads)

// Phase boundary: intentionally EMPTY. All phase deps are same-wave write->read
// through the SAME LDS array. HW processes a wave's LDS ops in order, and the
// compiler (a) preserves program order for may-alias LDS ops and (b) inserts
// counted lgkmcnt(N) waits before each read's use. The previous explicit
// "s_waitcnt lgkmcnt(0)" drained ALL outstanding ops ~12x/item and was the
// measured stall (R6/R8/R11: VALU cuts absorbed 1:1 by stalls at fixed 238us).
#define PB()

struct Params {
  const float* tl; const float* tr; const float* qemb;
  const float* ip_w1; const float* ip_b1;
  const float* bq2;
  const float* bo1; const float* bo2;
  const float* ffn_b1; const float* ffn_b2;
  const float* n1_g; const float* n1_b;
  const float* n2_g; const float* n2_b;
  const float* n3_g; const float* n3_b;
  const float* op_b1;
  const float* op_w2; const float* op_b2;
  const float* ws;
  float* out;
};

__global__ void prep1_kernel(const float* ip_w2, const float* ip_b2,
                             const float* wk2, const float* wv1, const float* wv2,
                             const float* bv1, const float* bv2, float* ws) {
  const int bid = blockIdx.x, tid = threadIdx.x;
  if (bid < 24) {
    const int idx = bid * 256 + tid;
    const int mat = idx >> 11;
    const int rem = idx & 2047;
    const int j = rem >> 6, c = rem & 63;
    const float* W = (mat == 0) ? wv1 : (mat == 1) ? wv2 : wk2;
    float acc = 0.f;
    for (int m = 0; m < 64; ++m) acc = fmaf(ip_w2[j * 64 + m], W[m * 64 + c], acc);
    if (mat == 0)      ws[WVF1F + j * 64 + c] = acc;
    else if (mat == 1) ws[WVF2F + j * 64 + c] = acc;
    else {
      ws[WKT2F + c * 32 + j] = acc * SCALE;
      ws[PKT2F + j * 64 + c] = acc * SCALE;
    }
  } else if (tid < 128) {
    const int l = tid >> 6, d = tid & 63;
    const float* bv = l ? bv2 : bv1;
    const float* wv = l ? wv2 : wv1;
    float acc = bv[d];
    for (int m = 0; m < 64; ++m) acc = fmaf(ip_b2[m], wv[m * 64 + d], acc);
    ws[(l ? BVF2F : BVF1F) + d] = acc;
  }
}

__global__ void prep2_kernel(const float* ip_w2, const float* wk1,
                             const float* qemb, const float* wq1, const float* bq1,
                             float* ws) {
  __shared__ float wkf[32][64];
  __shared__ float q1[3][64];
  const int tid = threadIdx.x;   // 384
  for (int e = tid; e < 2048; e += 384) {
    const int j = e >> 6, c = e & 63;
    float acc = 0.f;
    for (int m = 0; m < 64; ++m) acc = fmaf(ip_w2[j * 64 + m], wk1[m * 64 + c], acc);
    wkf[j][c] = acc;
  }
  if (tid < 192) {
    const int q = tid >> 6, d = tid & 63;
    float acc = bq1[d];
    for (int e = 0; e < 64; ++e) acc = fmaf(qemb[q * 64 + e], wq1[e * 64 + d], acc);
    q1[q][d] = acc;
  }
  __syncthreads();
  {
    const int r = tid >> 5, j = tid & 31;
    const int h = r / 3, q = r - h * 3;
    float acc = 0.f;
    for (int d = 0; d < 16; ++d) acc = fmaf(wkf[j][h * 16 + d], q1[q][h * 16 + d], acc);
    ws[G1F + r * 32 + j] = acc * SCALE;
  }
}

__global__ void prepC_kernel(float* ws,
                             const float* wq2, const float* wo1, const float* wo2,
                             const float* fw1, const float* fw2, const float* opw1) {
  const int e = blockIdx.x * 256 + threadIdx.x;
  if (e >= 34816) return;
  float v; int dst;
  if (e < 4096) {
    const int i = e, jc = i >> 8, rem = i & 255, d = rem >> 2, r = rem & 3;
    v = wq2[(jc * 4 + r) * 64 + d]; dst = PQ2 + i;
  } else if (e < 8192) {
    const int i = e - 4096, jc = i >> 8, rem = i & 255, d = rem >> 2, r = rem & 3;
    v = wo1[(jc * 4 + r) * 64 + d]; dst = PO1 + i;
  } else if (e < 12288) {
    const int i = e - 8192, jc = i >> 8, rem = i & 255, d = rem >> 2, r = rem & 3;
    v = wo2[(jc * 4 + r) * 64 + d]; dst = PO2 + i;
  } else if (e < 14336) {
    const int i = e - 12288, jc = i >> 8, rem = i & 255, d = rem >> 2, r = rem & 3;
    v = ws[WVF1F + (jc * 4 + r) * 64 + d]; dst = PV1 + i;
  } else if (e < 16384) {
    const int i = e - 14336, jc = i >> 8, rem = i & 255, d = rem >> 2, r = rem & 3;
    v = ws[WVF2F + (jc * 4 + r) * 64 + d]; dst = PV2 + i;
  } else if (e < 24576) {
    const int i = e - 16384, jc = i >> 9, rem = i & 511, d = rem >> 2, r = rem & 3;
    v = fw1[(jc * 4 + r) * 128 + d]; dst = PF1 + i;
  } else if (e < 32768) {
    const int i = e - 24576, mc = i >> 8, rem = i & 255, d = rem >> 2, r = rem & 3;
    v = fw2[(mc * 4 + r) * 64 + d]; dst = PF2 + i;
  } else {
    const int i = e - 32768, jc = i >> 7, rem = i & 127, d = rem >> 2, r = rem & 3;
    v = opw1[(jc * 4 + r) * 32 + d]; dst = POP1 + i;
  }
  ws[dst] = v;
}

// R11 configuration with phase drains REMOVED (see PB() comment).
__global__ __launch_bounds__(256) void planner_kernel(Params p) {
  const int w = threadIdx.x >> 6;
  const int lane = threadIdx.x & 63;
  const int item = blockIdx.x * 4 + w;

  __shared__ __align__(16) float g1_s[12][36];       // block-shared
  __shared__ __align__(16) float a_s[4][20][36];     // relu acts; later overlaid by f1[3][136]
  __shared__ __align__(16) float att_s[4][12][24];   // raw scores -> normalized probs
  __shared__ __align__(16) float ch_s[4][12][36];    // att@a; also holds g2
  __shared__ __align__(16) float qx_s[4][3][68];     // q2 / attn-out o / y1
  __shared__ __align__(16) float x_s[4][3][68];      // residual stream
  __shared__ float pts_s[4][40];

  const float* ws = p.ws;

  for (int e = threadIdx.x; e < 384; e += 256)
    g1_s[e >> 5][e & 31] = ws[G1F + e];

  if (lane < 40)
    pts_s[w][lane] = (lane < 20) ? p.tl[item * 20 + lane] : p.tr[item * 20 + lane - 20];
  PB();

  // a = relu(pts @ ip_w1 + ip_b1)   [20][32]
  {
    const int j = lane & 31, th = lane >> 5;
    const float w0 = p.ip_w1[j], w1 = p.ip_w1[32 + j], b = p.ip_b1[j];
#pragma unroll
    for (int i = 0; i < 10; ++i) {
      const int t = th * 10 + i;
      a_s[w][t][j] = fmaxf(fmaf(pts_s[w][2 * t], w0, fmaf(pts_s[w][2 * t + 1], w1, b)), 0.f);
    }
  }
  __syncthreads();  // covers g1_s (cross-wave) and a_s

  const int t3 = lane / 3;
  const int q3 = lane - t3 * 3;
  const int j32 = lane & 31, half = lane >> 5, hq0 = half * 6;
  const int h16 = lane >> 4;
  const int r12 = lane >> 2, sub = lane & 3;   // parallel softmax mapping

  float xq[3];

#pragma unroll
  for (int l = 0; l < 2; ++l) {
    if (l == 1) {
      // Q2 projection: lane = channel, packed float4 weights
      float acc[3];
#pragma unroll
      for (int q = 0; q < 3; ++q) acc[q] = p.bq2[lane];
#pragma unroll
      for (int jc = 0; jc < 16; ++jc) {
        const float4 w4 = *(const float4*)&ws[PQ2 + jc * 256 + lane * 4];
#pragma unroll
        for (int q = 0; q < 3; ++q) {
          const float4 xv = *(const float4*)&x_s[w][q][jc * 4];
          acc[q] = fmaf(xv.x, w4.x, fmaf(xv.y, w4.y, fmaf(xv.z, w4.z, fmaf(xv.w, w4.w, acc[q]))));
        }
      }
#pragma unroll
      for (int q = 0; q < 3; ++q) qx_s[w][q][lane] = acc[q];
      PB();
      // g2[hl*3+q][j] = sum_D PKT[j][D] * q2[q][D]  (float4 packed; SCALE folded)
      {
        float g2[6] = {0, 0, 0, 0, 0, 0};
        const int D0 = half * 32;
        const float* pkt = &ws[PKT2F + j32 * 64 + D0];
#pragma unroll
        for (int dd = 0; dd < 8; ++dd) {
          const float4 wk4 = *(const float4*)&pkt[dd * 4];
          const int hl = dd >> 2;
#pragma unroll
          for (int q = 0; q < 3; ++q) {
            const float4 q4 = *(const float4*)&qx_s[w][q][D0 + dd * 4];
            g2[hl * 3 + q] = fmaf(q4.x, wk4.x, fmaf(q4.y, wk4.y,
                              fmaf(q4.z, wk4.z, fmaf(q4.w, wk4.w, g2[hl * 3 + q]))));
          }
        }
#pragma unroll
        for (int k = 0; k < 6; ++k) ch_s[w][hq0 + k][j32] = g2[k];
      }
      PB();
    }

    // scores: lane=(t,q), s[h] = sum_j a[t][j] * g[h*3+q][j]
    const float (*g)[36] = (l == 0) ? (const float (*)[36])g1_s : (const float (*)[36])ch_s[w];
    if (lane < 60) {
      float acc[4] = {0, 0, 0, 0};
#pragma unroll
      for (int jc = 0; jc < 8; ++jc) {
        const float4 av = *(const float4*)&a_s[w][t3][jc * 4];
#pragma unroll
        for (int h = 0; h < 4; ++h) {
          const float4 gv = *(const float4*)&g[h * 3 + q3][jc * 4];
          acc[h] = fmaf(av.x, gv.x, fmaf(av.y, gv.y, fmaf(av.z, gv.z, fmaf(av.w, gv.w, acc[h]))));
        }
      }
#pragma unroll
      for (int h = 0; h < 4; ++h) att_s[w][h * 3 + q3][t3] = acc[h];
    }
    PB();

    // wave-parallel softmax: 4 lanes/row x 5 t each; writes normalized probs
    if (r12 < 12) {
      const int tb = sub * 5;
      float v0 = att_s[w][r12][tb],     v1 = att_s[w][r12][tb + 1];
      float v2 = att_s[w][r12][tb + 2], v3 = att_s[w][r12][tb + 3];
      float v4 = att_s[w][r12][tb + 4];
      float m = fmaxf(fmaxf(fmaxf(v0, v1), fmaxf(v2, v3)), v4);
      m = fmaxf(m, __shfl_xor(m, 1));
      m = fmaxf(m, __shfl_xor(m, 2));
      v0 = exp2f(v0 - m); v1 = exp2f(v1 - m); v2 = exp2f(v2 - m);
      v3 = exp2f(v3 - m); v4 = exp2f(v4 - m);
      float s = v0 + v1 + v2 + v3 + v4;
      s += __shfl_xor(s, 1);
      s += __shfl_xor(s, 2);
      const float inv = 1.f / s;
      att_s[w][r12][tb]     = v0 * inv;
      att_s[w][r12][tb + 1] = v1 * inv;
      att_s[w][r12][tb + 2] = v2 * inv;
      att_s[w][r12][tb + 3] = v3 * inv;
      att_s[w][r12][tb + 4] = v4 * inv;
    }
    PB();

    // ch[hq][j] = sum_t att[hq][t] * a[t][j]  (att pre-normalized)
    {
      float c[6] = {0, 0, 0, 0, 0, 0};
#pragma unroll
      for (int tc = 0; tc < 5; ++tc) {
        float av[4];
#pragma unroll
        for (int r = 0; r < 4; ++r) av[r] = a_s[w][tc * 4 + r][j32];
#pragma unroll
        for (int k = 0; k < 6; ++k) {
          const float4 at = *(const float4*)&att_s[w][hq0 + k][tc * 4];
          c[k] = fmaf(at.x, av[0], fmaf(at.y, av[1], fmaf(at.z, av[2], fmaf(at.w, av[3], c[k]))));
        }
      }
#pragma unroll
      for (int k = 0; k < 6; ++k) ch_s[w][hq0 + k][j32] = c[k];
    }
    PB();

    // o[q][d] = sum_j ch[h(d)*3+q][j] * Wvf[j][d] + bvf[d]  (packed Wv)
    {
      const int pv = l ? PV2 : PV1;
      const float bv = ws[(l ? BVF2F : BVF1F) + lane];
      float o[3] = {bv, bv, bv};
#pragma unroll
      for (int jc = 0; jc < 8; ++jc) {
        const float4 w4 = *(const float4*)&ws[pv + jc * 256 + lane * 4];
#pragma unroll
        for (int q = 0; q < 3; ++q) {
          const float4 cv = *(const float4*)&ch_s[w][h16 * 3 + q][jc * 4];
          o[q] = fmaf(cv.x, w4.x, fmaf(cv.y, w4.y, fmaf(cv.z, w4.z, fmaf(cv.w, w4.w, o[q]))));
        }
      }
#pragma unroll
      for (int q = 0; q < 3; ++q) qx_s[w][q][lane] = o[q];
    }
    PB();

    // O-proj + residual + LN  (packed wo)
    {
      const int po = l ? PO2 : PO1;
      const float* bo = l ? p.bo2 : p.bo1;
      const float* gg = l ? p.n2_g : p.n1_g;
      const float* gb = l ? p.n2_b : p.n1_b;
      float acc[3];
#pragma unroll
      for (int q = 0; q < 3; ++q)
        acc[q] = bo[lane] + (l ? xq[q] : p.qemb[q * 64 + lane]);
#pragma unroll
      for (int jc = 0; jc < 16; ++jc) {
        const float4 w4 = *(const float4*)&ws[po + jc * 256 + lane * 4];
#pragma unroll
        for (int q = 0; q < 3; ++q) {
          const float4 ov = *(const float4*)&qx_s[w][q][jc * 4];
          acc[q] = fmaf(ov.x, w4.x, fmaf(ov.y, w4.y, fmaf(ov.z, w4.z, fmaf(ov.w, w4.w, acc[q]))));
        }
      }
      const float gv = gg[lane], bv = gb[lane];
#pragma unroll
      for (int q = 0; q < 3; ++q) {
        const float v = acc[q];
        float s = v;
#pragma unroll
        for (int m = 32; m >= 1; m >>= 1) s += __shfl_xor(s, m);
        const float mu = s * (1.f / 64.f);
        const float d = v - mu;
        float s2 = d * d;
#pragma unroll
        for (int m = 32; m >= 1; m >>= 1) s2 += __shfl_xor(s2, m);
        const float inv = rsqrtf(s2 * (1.f / 64.f) + 1e-5f);
        const float xn = fmaf(d * inv, gv, bv);
        xq[q] = xn;
        x_s[w][q][lane] = xn;
      }
    }
    PB();
  }

  // FFN1: f1 = relu(x2 @ w1 + b1) -> overlay on a_s
  float* f1p = (float*)a_s[w];
  {
    float a0[3], a1[3];
    const float b0 = p.ffn_b1[lane], b1 = p.ffn_b1[64 + lane];
#pragma unroll
    for (int q = 0; q < 3; ++q) { a0[q] = b0; a1[q] = b1; }
#pragma unroll
    for (int jc = 0; jc < 16; ++jc) {
      const float4 w04 = *(const float4*)&ws[PF1 + jc * 512 + lane * 4];
      const float4 w14 = *(const float4*)&ws[PF1 + jc * 512 + 256 + lane * 4];
#pragma unroll
      for (int q = 0; q < 3; ++q) {
        const float4 xv = *(const float4*)&x_s[w][q][jc * 4];
        a0[q] = fmaf(xv.x, w04.x, fmaf(xv.y, w04.y, fmaf(xv.z, w04.z, fmaf(xv.w, w04.w, a0[q]))));
        a1[q] = fmaf(xv.x, w14.x, fmaf(xv.y, w14.y, fmaf(xv.z, w14.z, fmaf(xv.w, w14.w, a1[q]))));
      }
    }
#pragma unroll
    for (int q = 0; q < 3; ++q) {
      f1p[q * 136 + lane] = fmaxf(a0[q], 0.f);
      f1p[q * 136 + 64 + lane] = fmaxf(a1[q], 0.f);
    }
  }
  PB();

  // FFN2 + residual + LN3
  {
    float acc[3];
#pragma unroll
    for (int q = 0; q < 3; ++q) acc[q] = p.ffn_b2[lane] + xq[q];
#pragma unroll
    for (int mc = 0; mc < 32; ++mc) {
      const float4 w4 = *(const float4*)&ws[PF2 + mc * 256 + lane * 4];
#pragma unroll
      for (int q = 0; q < 3; ++q) {
        const float4 fv = *(const float4*)&f1p[q * 136 + mc * 4];
        acc[q] = fmaf(fv.x, w4.x, fmaf(fv.y, w4.y, fmaf(fv.z, w4.z, fmaf(fv.w, w4.w, acc[q]))));
      }
    }
    const float gv = p.n3_g[lane], bv = p.n3_b[lane];
#pragma unroll
    for (int q = 0; q < 3; ++q) {
      const float v = acc[q];
      float s = v;
#pragma unroll
      for (int m = 32; m >= 1; m >>= 1) s += __shfl_xor(s, m);
      const float mu = s * (1.f / 64.f);
      const float d = v - mu;
      float s2 = d * d;
#pragma unroll
      for (int m = 32; m >= 1; m >>= 1) s2 += __shfl_xor(s2, m);
      const float inv = rsqrtf(s2 * (1.f / 64.f) + 1e-5f);
      x_s[w][q][lane] = fmaf(d * inv, gv, bv);
    }
  }
  PB();

  // head 1: y1 = relu(x3 @ op_w1 + op_b1) [3][32]
  if (lane < 32) {
    float acc[3];
#pragma unroll
    for (int q = 0; q < 3; ++q) acc[q] = p.op_b1[lane];
#pragma unroll
    for (int jc = 0; jc < 16; ++jc) {
      const float4 w4 = *(const float4*)&ws[POP1 + jc * 128 + lane * 4];
#pragma unroll
      for (int q = 0; q < 3; ++q) {
        const float4 xv = *(const float4*)&x_s[w][q][jc * 4];
        acc[q] = fmaf(xv.x, w4.x, fmaf(xv.y, w4.y, fmaf(xv.z, w4.z, fmaf(xv.w, w4.w, acc[q]))));
      }
    }
#pragma unroll
    for (int q = 0; q < 3; ++q) qx_s[w][q][lane] = fmaxf(acc[q], 0.f);
  }
  PB();

  // head 2: 24 lanes (q,e,mg), 8 m each + quad reduce
  if (lane < 24) {
    const int q = lane >> 3, e = (lane >> 2) & 1, mg = lane & 3;
    float acc = 0.f;
#pragma unroll
    for (int k = 0; k < 8; ++k) {
      const int m = mg * 8 + k;
      acc = fmaf(qx_s[w][q][m], p.op_w2[m * 2 + e], acc);
    }
    acc += __shfl_xor(acc, 1);
    acc += __shfl_xor(acc, 2);
    if (mg == 0)
      p.out[item * 6 + q * 2 + e] = acc + p.op_b2[e];
  }
}

extern "C" void kernel_launch(void* const* d_in, const int* in_sizes, int n_in,
                              void* d_out, int out_size, void* d_ws, size_t ws_size,
                              hipStream_t stream) {
  const float* in[40];
  for (int i = 0; i < n_in && i < 40; ++i) in[i] = (const float*)d_in[i];

  const float *a1_wq, *a1_wk, *a1_wv, *a1_wo, *a1_bq, *a1_bk, *a1_bv, *a1_bo;
  const float *a2_wq, *a2_wk, *a2_wv, *a2_wo, *a2_bq, *a2_bk, *a2_bv, *a2_bo;
  if (in_sizes[8] == 4096) {
    a1_wq = in[7];  a1_wk = in[8];  a1_wv = in[9];  a1_wo = in[10];
    a1_bq = in[11]; a1_bk = in[12]; a1_bv = in[13]; a1_bo = in[14];
    a2_wq = in[15]; a2_wk = in[16]; a2_wv = in[17]; a2_wo = in[18];
    a2_bq = in[19]; a2_bk = in[20]; a2_bv = in[21]; a2_bo = in[22];
  } else {
    a1_wq = in[7];  a1_bq = in[8];  a1_wk = in[9];  a1_bk = in[10];
    a1_wv = in[11]; a1_bv = in[12]; a1_wo = in[13]; a1_bo = in[14];
    a2_wq = in[15]; a2_bq = in[16]; a2_wk = in[17]; a2_bk = in[18];
    a2_wv = in[19]; a2_bv = in[20]; a2_wo = in[21]; a2_bo = in[22];
  }
  (void)a1_bk; (void)a2_bk;  // K biases fold out of softmax exactly

  float* ws = (float*)d_ws;
  prep1_kernel<<<25, 256, 0, stream>>>(in[5], in[6], a2_wk, a1_wv, a2_wv, a1_bv, a2_bv, ws);
  prep2_kernel<<<1, 384, 0, stream>>>(in[5], a1_wk, in[2], a1_wq, a1_bq, ws);
  prepC_kernel<<<136, 256, 0, stream>>>(ws, a2_wq, a1_wo, a2_wo, in[23], in[25], in[33]);

  Params p;
  p.tl = in[0]; p.tr = in[1]; p.qemb = in[2];
  p.ip_w1 = in[3]; p.ip_b1 = in[4];
  p.bq2 = a2_bq;
  p.bo1 = a1_bo; p.bo2 = a2_bo;
  p.ffn_b1 = in[24]; p.ffn_b2 = in[26];
  p.n1_g = in[27]; p.n1_b = in[28]; p.n2_g = in[29]; p.n2_b = in[30];
  p.n3_g = in[31]; p.n3_b = in[32];
  p.op_b1 = in[34]; p.op_w2 = in[35]; p.op_b2 = in[36];
  p.ws = ws; p.out = (float*)d_out;

  planner_kernel<<<8192, 256, 0, stream>>>(p);
}

// Round 13
// 226.844 us; speedup vs baseline: 1.2844x; 1.0383x over previous
//
#include <hip/hip_runtime.h>
#include <math.h>

#define SCALE 0.36067376022224085f  // 0.25 * log2(e): folded attn scale for exp2-domain softmax

// ws float offsets
#define WVF1F 0      // [32][64] folded ip_w2@wv (layer1)
#define WVF2F 2048   // [32][64] layer2
#define WKT2F 4096   // [64][32] transposed folded ip_w2@wk2 * SCALE (legacy)
#define G1F   6144   // [12][32] g1 (layer-1 score weights)
#define BVF1F 6528   // [64] folded v bias layer1
#define BVF2F 6592   // [64] layer2
// packed float4 weight layouts: P*[jc*4d_stride + d*4 + r] = W[(jc*4+r)*D + d]
#define PQ2   6656
#define PO1   10752
#define PO2   14848
#define PV1   18944
#define PV2   20992
#define PF1   23040
#define PF2   31232
#define POP1  39424
#define PKT2F 41472  // [32j][64D] SCALE * Wkf2 row-major (float4 g2 reads)

// Phase boundary: intentionally EMPTY (R12, verified): all phase deps are
// same-wave write->read through the same LDS array; HW keeps a wave's LDS ops
// in order and the compiler inserts counted lgkmcnt waits.
#define PB()

// DPP butterfly steps (VALU pipe, not DS): quad xor1=0xB1, quad xor2=0x4E,
// row_half_mirror=0x141 (pairs quads 0-1 / 2-3 once quads are uniform),
// row_mirror=0x140 (pairs row halves). Masks 16/32 remain __shfl_xor (DS).
template <int C>
__device__ __forceinline__ float dppadd(float x) {
  return x + __builtin_bit_cast(float, __builtin_amdgcn_update_dpp(
                 0, __builtin_bit_cast(int, x), C, 0xf, 0xf, true));
}
template <int C>
__device__ __forceinline__ float dppmax(float x) {
  return fmaxf(x, __builtin_bit_cast(float, __builtin_amdgcn_update_dpp(
                      0, __builtin_bit_cast(int, x), C, 0xf, 0xf, true)));
}
__device__ __forceinline__ float wsum64(float s) {
  s = dppadd<0xB1>(s);
  s = dppadd<0x4E>(s);
  s = dppadd<0x141>(s);
  s = dppadd<0x140>(s);
  s += __shfl_xor(s, 16);
  s += __shfl_xor(s, 32);
  return s;
}

struct Params {
  const float* tl; const float* tr; const float* qemb;
  const float* ip_w1; const float* ip_b1;
  const float* bq2;
  const float* bo1; const float* bo2;
  const float* ffn_b1; const float* ffn_b2;
  const float* n1_g; const float* n1_b;
  const float* n2_g; const float* n2_b;
  const float* n3_g; const float* n3_b;
  const float* op_b1;
  const float* op_w2; const float* op_b2;
  const float* ws;
  float* out;
};

__global__ void prep1_kernel(const float* ip_w2, const float* ip_b2,
                             const float* wk2, const float* wv1, const float* wv2,
                             const float* bv1, const float* bv2, float* ws) {
  const int bid = blockIdx.x, tid = threadIdx.x;
  if (bid < 24) {
    const int idx = bid * 256 + tid;
    const int mat = idx >> 11;
    const int rem = idx & 2047;
    const int j = rem >> 6, c = rem & 63;
    const float* W = (mat == 0) ? wv1 : (mat == 1) ? wv2 : wk2;
    float acc = 0.f;
    for (int m = 0; m < 64; ++m) acc = fmaf(ip_w2[j * 64 + m], W[m * 64 + c], acc);
    if (mat == 0)      ws[WVF1F + j * 64 + c] = acc;
    else if (mat == 1) ws[WVF2F + j * 64 + c] = acc;
    else {
      ws[WKT2F + c * 32 + j] = acc * SCALE;
      ws[PKT2F + j * 64 + c] = acc * SCALE;
    }
  } else if (tid < 128) {
    const int l = tid >> 6, d = tid & 63;
    const float* bv = l ? bv2 : bv1;
    const float* wv = l ? wv2 : wv1;
    float acc = bv[d];
    for (int m = 0; m < 64; ++m) acc = fmaf(ip_b2[m], wv[m * 64 + d], acc);
    ws[(l ? BVF2F : BVF1F) + d] = acc;
  }
}

__global__ void prep2_kernel(const float* ip_w2, const float* wk1,
                             const float* qemb, const float* wq1, const float* bq1,
                             float* ws) {
  __shared__ float wkf[32][64];
  __shared__ float q1[3][64];
  const int tid = threadIdx.x;   // 384
  for (int e = tid; e < 2048; e += 384) {
    const int j = e >> 6, c = e & 63;
    float acc = 0.f;
    for (int m = 0; m < 64; ++m) acc = fmaf(ip_w2[j * 64 + m], wk1[m * 64 + c], acc);
    wkf[j][c] = acc;
  }
  if (tid < 192) {
    const int q = tid >> 6, d = tid & 63;
    float acc = bq1[d];
    for (int e = 0; e < 64; ++e) acc = fmaf(qemb[q * 64 + e], wq1[e * 64 + d], acc);
    q1[q][d] = acc;
  }
  __syncthreads();
  {
    const int r = tid >> 5, j = tid & 31;
    const int h = r / 3, q = r - h * 3;
    float acc = 0.f;
    for (int d = 0; d < 16; ++d) acc = fmaf(wkf[j][h * 16 + d], q1[q][h * 16 + d], acc);
    ws[G1F + r * 32 + j] = acc * SCALE;
  }
}

__global__ void prepC_kernel(float* ws,
                             const float* wq2, const float* wo1, const float* wo2,
                             const float* fw1, const float* fw2, const float* opw1) {
  const int e = blockIdx.x * 256 + threadIdx.x;
  if (e >= 34816) return;
  float v; int dst;
  if (e < 4096) {
    const int i = e, jc = i >> 8, rem = i & 255, d = rem >> 2, r = rem & 3;
    v = wq2[(jc * 4 + r) * 64 + d]; dst = PQ2 + i;
  } else if (e < 8192) {
    const int i = e - 4096, jc = i >> 8, rem = i & 255, d = rem >> 2, r = rem & 3;
    v = wo1[(jc * 4 + r) * 64 + d]; dst = PO1 + i;
  } else if (e < 12288) {
    const int i = e - 8192, jc = i >> 8, rem = i & 255, d = rem >> 2, r = rem & 3;
    v = wo2[(jc * 4 + r) * 64 + d]; dst = PO2 + i;
  } else if (e < 14336) {
    const int i = e - 12288, jc = i >> 8, rem = i & 255, d = rem >> 2, r = rem & 3;
    v = ws[WVF1F + (jc * 4 + r) * 64 + d]; dst = PV1 + i;
  } else if (e < 16384) {
    const int i = e - 14336, jc = i >> 8, rem = i & 255, d = rem >> 2, r = rem & 3;
    v = ws[WVF2F + (jc * 4 + r) * 64 + d]; dst = PV2 + i;
  } else if (e < 24576) {
    const int i = e - 16384, jc = i >> 9, rem = i & 511, d = rem >> 2, r = rem & 3;
    v = fw1[(jc * 4 + r) * 128 + d]; dst = PF1 + i;
  } else if (e < 32768) {
    const int i = e - 24576, mc = i >> 8, rem = i & 255, d = rem >> 2, r = rem & 3;
    v = fw2[(mc * 4 + r) * 64 + d]; dst = PF2 + i;
  } else {
    const int i = e - 32768, jc = i >> 7, rem = i & 127, d = rem >> 2, r = rem & 3;
    v = opw1[(jc * 4 + r) * 32 + d]; dst = POP1 + i;
  }
  ws[dst] = v;
}

// R12 base + DPP reductions (LN/softmax/head2 shuffles moved DS->VALU) +
// merged LN moments (var = E[v^2]-mu^2: one 6-deep chain instead of two).
__global__ __launch_bounds__(256) void planner_kernel(Params p) {
  const int w = threadIdx.x >> 6;
  const int lane = threadIdx.x & 63;
  const int item = blockIdx.x * 4 + w;

  __shared__ __align__(16) float g1_s[12][36];       // block-shared
  __shared__ __align__(16) float a_s[4][20][36];     // relu acts; later overlaid by f1[3][136]
  __shared__ __align__(16) float att_s[4][12][24];   // raw scores -> normalized probs
  __shared__ __align__(16) float ch_s[4][12][36];    // att@a; also holds g2
  __shared__ __align__(16) float qx_s[4][3][68];     // q2 / attn-out o / y1
  __shared__ __align__(16) float x_s[4][3][68];      // residual stream
  __shared__ float pts_s[4][40];

  const float* ws = p.ws;

  for (int e = threadIdx.x; e < 384; e += 256)
    g1_s[e >> 5][e & 31] = ws[G1F + e];

  if (lane < 40)
    pts_s[w][lane] = (lane < 20) ? p.tl[item * 20 + lane] : p.tr[item * 20 + lane - 20];
  PB();

  // a = relu(pts @ ip_w1 + ip_b1)   [20][32]
  {
    const int j = lane & 31, th = lane >> 5;
    const float w0 = p.ip_w1[j], w1 = p.ip_w1[32 + j], b = p.ip_b1[j];
#pragma unroll
    for (int i = 0; i < 10; ++i) {
      const int t = th * 10 + i;
      a_s[w][t][j] = fmaxf(fmaf(pts_s[w][2 * t], w0, fmaf(pts_s[w][2 * t + 1], w1, b)), 0.f);
    }
  }
  __syncthreads();  // covers g1_s (cross-wave) and a_s

  const int t3 = lane / 3;
  const int q3 = lane - t3 * 3;
  const int j32 = lane & 31, half = lane >> 5, hq0 = half * 6;
  const int h16 = lane >> 4;
  const int r12 = lane >> 2, sub = lane & 3;   // parallel softmax mapping

  float xq[3];

#pragma unroll
  for (int l = 0; l < 2; ++l) {
    if (l == 1) {
      // Q2 projection: lane = channel, packed float4 weights
      float acc[3];
#pragma unroll
      for (int q = 0; q < 3; ++q) acc[q] = p.bq2[lane];
#pragma unroll
      for (int jc = 0; jc < 16; ++jc) {
        const float4 w4 = *(const float4*)&ws[PQ2 + jc * 256 + lane * 4];
#pragma unroll
        for (int q = 0; q < 3; ++q) {
          const float4 xv = *(const float4*)&x_s[w][q][jc * 4];
          acc[q] = fmaf(xv.x, w4.x, fmaf(xv.y, w4.y, fmaf(xv.z, w4.z, fmaf(xv.w, w4.w, acc[q]))));
        }
      }
#pragma unroll
      for (int q = 0; q < 3; ++q) qx_s[w][q][lane] = acc[q];
      PB();
      // g2[hl*3+q][j] = sum_D PKT[j][D] * q2[q][D]  (float4 packed; SCALE folded)
      {
        float g2[6] = {0, 0, 0, 0, 0, 0};
        const int D0 = half * 32;
        const float* pkt = &ws[PKT2F + j32 * 64 + D0];
#pragma unroll
        for (int dd = 0; dd < 8; ++dd) {
          const float4 wk4 = *(const float4*)&pkt[dd * 4];
          const int hl = dd >> 2;
#pragma unroll
          for (int q = 0; q < 3; ++q) {
            const float4 q4 = *(const float4*)&qx_s[w][q][D0 + dd * 4];
            g2[hl * 3 + q] = fmaf(q4.x, wk4.x, fmaf(q4.y, wk4.y,
                              fmaf(q4.z, wk4.z, fmaf(q4.w, wk4.w, g2[hl * 3 + q]))));
          }
        }
#pragma unroll
        for (int k = 0; k < 6; ++k) ch_s[w][hq0 + k][j32] = g2[k];
      }
      PB();
    }

    // scores: lane=(t,q), s[h] = sum_j a[t][j] * g[h*3+q][j]
    const float (*g)[36] = (l == 0) ? (const float (*)[36])g1_s : (const float (*)[36])ch_s[w];
    if (lane < 60) {
      float acc[4] = {0, 0, 0, 0};
#pragma unroll
      for (int jc = 0; jc < 8; ++jc) {
        const float4 av = *(const float4*)&a_s[w][t3][jc * 4];
#pragma unroll
        for (int h = 0; h < 4; ++h) {
          const float4 gv = *(const float4*)&g[h * 3 + q3][jc * 4];
          acc[h] = fmaf(av.x, gv.x, fmaf(av.y, gv.y, fmaf(av.z, gv.z, fmaf(av.w, gv.w, acc[h]))));
        }
      }
#pragma unroll
      for (int h = 0; h < 4; ++h) att_s[w][h * 3 + q3][t3] = acc[h];
    }
    PB();

    // wave-parallel softmax: 4 lanes/row x 5 t each; quad-reduce on DPP (VALU)
    if (r12 < 12) {
      const int tb = sub * 5;
      float v0 = att_s[w][r12][tb],     v1 = att_s[w][r12][tb + 1];
      float v2 = att_s[w][r12][tb + 2], v3 = att_s[w][r12][tb + 3];
      float v4 = att_s[w][r12][tb + 4];
      float m = fmaxf(fmaxf(fmaxf(v0, v1), fmaxf(v2, v3)), v4);
      m = dppmax<0xB1>(m);
      m = dppmax<0x4E>(m);
      v0 = exp2f(v0 - m); v1 = exp2f(v1 - m); v2 = exp2f(v2 - m);
      v3 = exp2f(v3 - m); v4 = exp2f(v4 - m);
      float s = v0 + v1 + v2 + v3 + v4;
      s = dppadd<0xB1>(s);
      s = dppadd<0x4E>(s);
      const float inv = 1.f / s;
      att_s[w][r12][tb]     = v0 * inv;
      att_s[w][r12][tb + 1] = v1 * inv;
      att_s[w][r12][tb + 2] = v2 * inv;
      att_s[w][r12][tb + 3] = v3 * inv;
      att_s[w][r12][tb + 4] = v4 * inv;
    }
    PB();

    // ch[hq][j] = sum_t att[hq][t] * a[t][j]  (att pre-normalized)
    {
      float c[6] = {0, 0, 0, 0, 0, 0};
#pragma unroll
      for (int tc = 0; tc < 5; ++tc) {
        float av[4];
#pragma unroll
        for (int r = 0; r < 4; ++r) av[r] = a_s[w][tc * 4 + r][j32];
#pragma unroll
        for (int k = 0; k < 6; ++k) {
          const float4 at = *(const float4*)&att_s[w][hq0 + k][tc * 4];
          c[k] = fmaf(at.x, av[0], fmaf(at.y, av[1], fmaf(at.z, av[2], fmaf(at.w, av[3], c[k]))));
        }
      }
#pragma unroll
      for (int k = 0; k < 6; ++k) ch_s[w][hq0 + k][j32] = c[k];
    }
    PB();

    // o[q][d] = sum_j ch[h(d)*3+q][j] * Wvf[j][d] + bvf[d]  (packed Wv)
    {
      const int pv = l ? PV2 : PV1;
      const float bv = ws[(l ? BVF2F : BVF1F) + lane];
      float o[3] = {bv, bv, bv};
#pragma unroll
      for (int jc = 0; jc < 8; ++jc) {
        const float4 w4 = *(const float4*)&ws[pv + jc * 256 + lane * 4];
#pragma unroll
        for (int q = 0; q < 3; ++q) {
          const float4 cv = *(const float4*)&ch_s[w][h16 * 3 + q][jc * 4];
          o[q] = fmaf(cv.x, w4.x, fmaf(cv.y, w4.y, fmaf(cv.z, w4.z, fmaf(cv.w, w4.w, o[q]))));
        }
      }
#pragma unroll
      for (int q = 0; q < 3; ++q) qx_s[w][q][lane] = o[q];
    }
    PB();

    // O-proj + residual + LN  (packed wo; merged-moment DPP reduction)
    {
      const int po = l ? PO2 : PO1;
      const float* bo = l ? p.bo2 : p.bo1;
      const float* gg = l ? p.n2_g : p.n1_g;
      const float* gb = l ? p.n2_b : p.n1_b;
      float acc[3];
#pragma unroll
      for (int q = 0; q < 3; ++q)
        acc[q] = bo[lane] + (l ? xq[q] : p.qemb[q * 64 + lane]);
#pragma unroll
      for (int jc = 0; jc < 16; ++jc) {
        const float4 w4 = *(const float4*)&ws[po + jc * 256 + lane * 4];
#pragma unroll
        for (int q = 0; q < 3; ++q) {
          const float4 ov = *(const float4*)&qx_s[w][q][jc * 4];
          acc[q] = fmaf(ov.x, w4.x, fmaf(ov.y, w4.y, fmaf(ov.z, w4.z, fmaf(ov.w, w4.w, acc[q]))));
        }
      }
      const float gv = gg[lane], bv = gb[lane];
#pragma unroll
      for (int q = 0; q < 3; ++q) {
        const float v = acc[q];
        const float s = wsum64(v);
        const float s2 = wsum64(v * v);
        const float mu = s * (1.f / 64.f);
        const float var = fmaf(s2, 1.f / 64.f, -mu * mu);
        const float inv = rsqrtf(var + 1e-5f);
        const float xn = fmaf((v - mu) * inv, gv, bv);
        xq[q] = xn;
        x_s[w][q][lane] = xn;
      }
    }
    PB();
  }

  // FFN1: f1 = relu(x2 @ w1 + b1) -> overlay on a_s
  float* f1p = (float*)a_s[w];
  {
    float a0[3], a1[3];
    const float b0 = p.ffn_b1[lane], b1 = p.ffn_b1[64 + lane];
#pragma unroll
    for (int q = 0; q < 3; ++q) { a0[q] = b0; a1[q] = b1; }
#pragma unroll
    for (int jc = 0; jc < 16; ++jc) {
      const float4 w04 = *(const float4*)&ws[PF1 + jc * 512 + lane * 4];
      const float4 w14 = *(const float4*)&ws[PF1 + jc * 512 + 256 + lane * 4];
#pragma unroll
      for (int q = 0; q < 3; ++q) {
        const float4 xv = *(const float4*)&x_s[w][q][jc * 4];
        a0[q] = fmaf(xv.x, w04.x, fmaf(xv.y, w04.y, fmaf(xv.z, w04.z, fmaf(xv.w, w04.w, a0[q]))));
        a1[q] = fmaf(xv.x, w14.x, fmaf(xv.y, w14.y, fmaf(xv.z, w14.z, fmaf(xv.w, w14.w, a1[q]))));
      }
    }
#pragma unroll
    for (int q = 0; q < 3; ++q) {
      f1p[q * 136 + lane] = fmaxf(a0[q], 0.f);
      f1p[q * 136 + 64 + lane] = fmaxf(a1[q], 0.f);
    }
  }
  PB();

  // FFN2 + residual + LN3
  {
    float acc[3];
#pragma unroll
    for (int q = 0; q < 3; ++q) acc[q] = p.ffn_b2[lane] + xq[q];
#pragma unroll
    for (int mc = 0; mc < 32; ++mc) {
      const float4 w4 = *(const float4*)&ws[PF2 + mc * 256 + lane * 4];
#pragma unroll
      for (int q = 0; q < 3; ++q) {
        const float4 fv = *(const float4*)&f1p[q * 136 + mc * 4];
        acc[q] = fmaf(fv.x, w4.x, fmaf(fv.y, w4.y, fmaf(fv.z, w4.z, fmaf(fv.w, w4.w, acc[q]))));
      }
    }
    const float gv = p.n3_g[lane], bv = p.n3_b[lane];
#pragma unroll
    for (int q = 0; q < 3; ++q) {
      const float v = acc[q];
      const float s = wsum64(v);
      const float s2 = wsum64(v * v);
      const float mu = s * (1.f / 64.f);
      const float var = fmaf(s2, 1.f / 64.f, -mu * mu);
      const float inv = rsqrtf(var + 1e-5f);
      x_s[w][q][lane] = fmaf((v - mu) * inv, gv, bv);
    }
  }
  PB();

  // head 1: y1 = relu(x3 @ op_w1 + op_b1) [3][32]
  if (lane < 32) {
    float acc[3];
#pragma unroll
    for (int q = 0; q < 3; ++q) acc[q] = p.op_b1[lane];
#pragma unroll
    for (int jc = 0; jc < 16; ++jc) {
      const float4 w4 = *(const float4*)&ws[POP1 + jc * 128 + lane * 4];
#pragma unroll
      for (int q = 0; q < 3; ++q) {
        const float4 xv = *(const float4*)&x_s[w][q][jc * 4];
        acc[q] = fmaf(xv.x, w4.x, fmaf(xv.y, w4.y, fmaf(xv.z, w4.z, fmaf(xv.w, w4.w, acc[q]))));
      }
    }
#pragma unroll
    for (int q = 0; q < 3; ++q) qx_s[w][q][lane] = fmaxf(acc[q], 0.f);
  }
  PB();

  // head 2: 24 lanes (q,e,mg), 8 m each + DPP quad reduce
  if (lane < 24) {
    const int q = lane >> 3, e = (lane >> 2) & 1, mg = lane & 3;
    float acc = 0.f;
#pragma unroll
    for (int k = 0; k < 8; ++k) {
      const int m = mg * 8 + k;
      acc = fmaf(qx_s[w][q][m], p.op_w2[m * 2 + e], acc);
    }
    acc = dppadd<0xB1>(acc);
    acc = dppadd<0x4E>(acc);
    if (mg == 0)
      p.out[item * 6 + q * 2 + e] = acc + p.op_b2[e];
  }
}

extern "C" void kernel_launch(void* const* d_in, const int* in_sizes, int n_in,
                              void* d_out, int out_size, void* d_ws, size_t ws_size,
                              hipStream_t stream) {
  const float* in[40];
  for (int i = 0; i < n_in && i < 40; ++i) in[i] = (const float*)d_in[i];

  const float *a1_wq, *a1_wk, *a1_wv, *a1_wo, *a1_bq, *a1_bk, *a1_bv, *a1_bo;
  const float *a2_wq, *a2_wk, *a2_wv, *a2_wo, *a2_bq, *a2_bk, *a2_bv, *a2_bo;
  if (in_sizes[8] == 4096) {
    a1_wq = in[7];  a1_wk = in[8];  a1_wv = in[9];  a1_wo = in[10];
    a1_bq = in[11]; a1_bk = in[12]; a1_bv = in[13]; a1_bo = in[14];
    a2_wq = in[15]; a2_wk = in[16]; a2_wv = in[17]; a2_wo = in[18];
    a2_bq = in[19]; a2_bk = in[20]; a2_bv = in[21]; a2_bo = in[22];
  } else {
    a1_wq = in[7];  a1_bq = in[8];  a1_wk = in[9];  a1_bk = in[10];
    a1_wv = in[11]; a1_bv = in[12]; a1_wo = in[13]; a1_bo = in[14];
    a2_wq = in[15]; a2_bq = in[16]; a2_wk = in[17]; a2_bk = in[18];
    a2_wv = in[19]; a2_bv = in[20]; a2_wo = in[21]; a2_bo = in[22];
  }
  (void)a1_bk; (void)a2_bk;  // K biases fold out of softmax exactly

  float* ws = (float*)d_ws;
  prep1_kernel<<<25, 256, 0, stream>>>(in[5], in[6], a2_wk, a1_wv, a2_wv, a1_bv, a2_bv, ws);
  prep2_kernel<<<1, 384, 0, stream>>>(in[5], a1_wk, in[2], a1_wq, a1_bq, ws);
  prepC_kernel<<<136, 256, 0, stream>>>(ws, a2_wq, a1_wo, a2_wo, in[23], in[25], in[33]);

  Params p;
  p.tl = in[0]; p.tr = in[1]; p.qemb = in[2];
  p.ip_w1 = in[3]; p.ip_b1 = in[4];
  p.bq2 = a2_bq;
  p.bo1 = a1_bo; p.bo2 = a2_bo;
  p.ffn_b1 = in[24]; p.ffn_b2 = in[26];
  p.n1_g = in[27]; p.n1_b = in[28]; p.n2_g = in[29]; p.n2_b = in[30];
  p.n3_g = in[31]; p.n3_b = in[32];
  p.op_b1 = in[34]; p.op_w2 = in[35]; p.op_b2 = in[36];
  p.ws = ws; p.out = (float*)d_out;

  planner_kernel<<<8192, 256, 0, stream>>>(p);
}

// Round 14
// 218.806 us; speedup vs baseline: 1.3315x; 1.0367x over previous
//
#include <hip/hip_runtime.h>
#include <math.h>

#define SCALE 0.36067376022224085f  // 0.25 * log2(e): folded attn scale for exp2-domain softmax

// ws float offsets
#define WVF1F 0      // [32][64] folded ip_w2@wv (layer1)
#define WVF2F 2048   // [32][64] layer2
#define G1F   6144   // [12][32] g1 (layer-1 score weights)
#define BVF1F 6528   // [64] folded v bias layer1
#define BVF2F 6592   // [64] layer2
// packed float4 weight layouts: P*[jc*4d_stride + d*4 + r] = W[(jc*4+r)*D + d]
#define PQ2   6656
#define PO1   10752
#define PO2   14848
#define PV1   18944
#define PV2   20992
#define PF1   23040
#define PF2   31232
#define POP1  39424
#define PKT2F 41472  // [32j][64D] SCALE * Wkf2 row-major (float4 g2 reads)

// Phase boundary: intentionally EMPTY (R12, verified): all phase deps are
// same-wave write->read through the same LDS array; HW keeps a wave's LDS ops
// in order and the compiler inserts counted lgkmcnt waits.
#define PB()

// DPP butterfly steps (VALU pipe, not DS): quad xor1=0xB1, quad xor2=0x4E,
// row_half_mirror=0x141, row_mirror=0x140. Masks 16/32 remain __shfl_xor (DS).
template <int C>
__device__ __forceinline__ float dppadd(float x) {
  return x + __builtin_bit_cast(float, __builtin_amdgcn_update_dpp(
                 0, __builtin_bit_cast(int, x), C, 0xf, 0xf, true));
}
template <int C>
__device__ __forceinline__ float dppmax(float x) {
  return fmaxf(x, __builtin_bit_cast(float, __builtin_amdgcn_update_dpp(
                      0, __builtin_bit_cast(int, x), C, 0xf, 0xf, true)));
}
__device__ __forceinline__ float wsum64(float s) {
  s = dppadd<0xB1>(s);
  s = dppadd<0x4E>(s);
  s = dppadd<0x141>(s);
  s = dppadd<0x140>(s);
  s += __shfl_xor(s, 16);
  s += __shfl_xor(s, 32);
  return s;
}
// full reduce over lanes 0..31 (caller guarantees lane<32 active)
__device__ __forceinline__ float wsum32(float s) {
  s = dppadd<0xB1>(s);
  s = dppadd<0x4E>(s);
  s = dppadd<0x141>(s);
  s = dppadd<0x140>(s);
  s += __shfl_xor(s, 16);
  return s;
}

struct Params {
  const float* tl; const float* tr; const float* qemb;
  const float* ip_w1; const float* ip_b1;
  const float* bq2;
  const float* bo1; const float* bo2;
  const float* ffn_b1; const float* ffn_b2;
  const float* n1_g; const float* n1_b;
  const float* n2_g; const float* n2_b;
  const float* n3_g; const float* n3_b;
  const float* op_b1;
  const float* op_w2; const float* op_b2;
  const float* ws;
  float* out;
};

// Merged prep1+prep2: blocks 0-23 = weight folds, block 24 = v-bias folds,
// block 25 = g1 (prep2 body, needs all 384 threads + __syncthreads).
__global__ void prep12_kernel(const float* ip_w2, const float* ip_b2,
                              const float* wk1, const float* wk2,
                              const float* wv1, const float* wv2,
                              const float* bv1, const float* bv2,
                              const float* qemb, const float* wq1, const float* bq1,
                              float* ws) {
  const int bid = blockIdx.x, tid = threadIdx.x;  // 26 blocks x 384 threads
  if (bid < 24) {
    if (tid < 256) {
      const int idx = bid * 256 + tid;      // 0..6143
      const int mat = idx >> 11;
      const int rem = idx & 2047;
      const int j = rem >> 6, c = rem & 63;
      const float* W = (mat == 0) ? wv1 : (mat == 1) ? wv2 : wk2;
      float acc = 0.f;
      for (int m = 0; m < 64; ++m) acc = fmaf(ip_w2[j * 64 + m], W[m * 64 + c], acc);
      if (mat == 0)      ws[WVF1F + j * 64 + c] = acc;
      else if (mat == 1) ws[WVF2F + j * 64 + c] = acc;
      else               ws[PKT2F + j * 64 + c] = acc * SCALE;
    }
  } else if (bid == 24) {
    if (tid < 128) {
      const int l = tid >> 6, d = tid & 63;
      const float* bv = l ? bv2 : bv1;
      const float* wv = l ? wv2 : wv1;
      float acc = bv[d];
      for (int m = 0; m < 64; ++m) acc = fmaf(ip_b2[m], wv[m * 64 + d], acc);
      ws[(l ? BVF2F : BVF1F) + d] = acc;
    }
  } else {
    // g1[h*3+q][j] = SCALE * sum_d Wkf1[j][h*16+d] * q1[q][h*16+d]
    __shared__ float wkf[32][64];
    __shared__ float q1[3][64];
    for (int e = tid; e < 2048; e += 384) {
      const int j = e >> 6, c = e & 63;
      float acc = 0.f;
      for (int m = 0; m < 64; ++m) acc = fmaf(ip_w2[j * 64 + m], wk1[m * 64 + c], acc);
      wkf[j][c] = acc;
    }
    if (tid < 192) {
      const int q = tid >> 6, d = tid & 63;
      float acc = bq1[d];
      for (int e = 0; e < 64; ++e) acc = fmaf(qemb[q * 64 + e], wq1[e * 64 + d], acc);
      q1[q][d] = acc;
    }
    __syncthreads();
    {
      const int r = tid >> 5, j = tid & 31;
      const int h = r / 3, q = r - h * 3;
      float acc = 0.f;
      for (int d = 0; d < 16; ++d) acc = fmaf(wkf[j][h * 16 + d], q1[q][h * 16 + d], acc);
      ws[G1F + r * 32 + j] = acc * SCALE;
    }
  }
}

__global__ void prepC_kernel(float* ws,
                             const float* wq2, const float* wo1, const float* wo2,
                             const float* fw1, const float* fw2, const float* opw1) {
  const int e = blockIdx.x * 256 + threadIdx.x;
  if (e >= 34816) return;
  float v; int dst;
  if (e < 4096) {
    const int i = e, jc = i >> 8, rem = i & 255, d = rem >> 2, r = rem & 3;
    v = wq2[(jc * 4 + r) * 64 + d]; dst = PQ2 + i;
  } else if (e < 8192) {
    const int i = e - 4096, jc = i >> 8, rem = i & 255, d = rem >> 2, r = rem & 3;
    v = wo1[(jc * 4 + r) * 64 + d]; dst = PO1 + i;
  } else if (e < 12288) {
    const int i = e - 8192, jc = i >> 8, rem = i & 255, d = rem >> 2, r = rem & 3;
    v = wo2[(jc * 4 + r) * 64 + d]; dst = PO2 + i;
  } else if (e < 14336) {
    const int i = e - 12288, jc = i >> 8, rem = i & 255, d = rem >> 2, r = rem & 3;
    v = ws[WVF1F + (jc * 4 + r) * 64 + d]; dst = PV1 + i;
  } else if (e < 16384) {
    const int i = e - 14336, jc = i >> 8, rem = i & 255, d = rem >> 2, r = rem & 3;
    v = ws[WVF2F + (jc * 4 + r) * 64 + d]; dst = PV2 + i;
  } else if (e < 24576) {
    const int i = e - 16384, jc = i >> 9, rem = i & 511, d = rem >> 2, r = rem & 3;
    v = fw1[(jc * 4 + r) * 128 + d]; dst = PF1 + i;
  } else if (e < 32768) {
    const int i = e - 24576, mc = i >> 8, rem = i & 255, d = rem >> 2, r = rem & 3;
    v = fw2[(mc * 4 + r) * 64 + d]; dst = PF2 + i;
  } else {
    const int i = e - 32768, jc = i >> 7, rem = i & 127, d = rem >> 2, r = rem & 3;
    v = opw1[(jc * 4 + r) * 32 + d]; dst = POP1 + i;
  }
  ws[dst] = v;
}

// R13 base + fused head1/head2 (y1 in regs, 32-lane DPP reductions, lane-0 store).
__global__ __launch_bounds__(256) void planner_kernel(Params p) {
  const int w = threadIdx.x >> 6;
  const int lane = threadIdx.x & 63;
  const int item = blockIdx.x * 4 + w;

  __shared__ __align__(16) float g1_s[12][36];       // block-shared
  __shared__ __align__(16) float a_s[4][20][36];     // relu acts; later overlaid by f1[3][136]
  __shared__ __align__(16) float att_s[4][12][24];   // raw scores -> normalized probs
  __shared__ __align__(16) float ch_s[4][12][36];    // att@a; also holds g2
  __shared__ __align__(16) float qx_s[4][3][68];     // q2 / attn-out o
  __shared__ __align__(16) float x_s[4][3][68];      // residual stream
  __shared__ float pts_s[4][40];

  const float* ws = p.ws;

  for (int e = threadIdx.x; e < 384; e += 256)
    g1_s[e >> 5][e & 31] = ws[G1F + e];

  if (lane < 40)
    pts_s[w][lane] = (lane < 20) ? p.tl[item * 20 + lane] : p.tr[item * 20 + lane - 20];
  PB();

  // a = relu(pts @ ip_w1 + ip_b1)   [20][32]
  {
    const int j = lane & 31, th = lane >> 5;
    const float w0 = p.ip_w1[j], w1 = p.ip_w1[32 + j], b = p.ip_b1[j];
#pragma unroll
    for (int i = 0; i < 10; ++i) {
      const int t = th * 10 + i;
      a_s[w][t][j] = fmaxf(fmaf(pts_s[w][2 * t], w0, fmaf(pts_s[w][2 * t + 1], w1, b)), 0.f);
    }
  }
  __syncthreads();  // covers g1_s (cross-wave) and a_s

  const int t3 = lane / 3;
  const int q3 = lane - t3 * 3;
  const int j32 = lane & 31, half = lane >> 5, hq0 = half * 6;
  const int h16 = lane >> 4;
  const int r12 = lane >> 2, sub = lane & 3;   // parallel softmax mapping

  float xq[3];

#pragma unroll
  for (int l = 0; l < 2; ++l) {
    if (l == 1) {
      // Q2 projection: lane = channel, packed float4 weights
      float acc[3];
#pragma unroll
      for (int q = 0; q < 3; ++q) acc[q] = p.bq2[lane];
#pragma unroll
      for (int jc = 0; jc < 16; ++jc) {
        const float4 w4 = *(const float4*)&ws[PQ2 + jc * 256 + lane * 4];
#pragma unroll
        for (int q = 0; q < 3; ++q) {
          const float4 xv = *(const float4*)&x_s[w][q][jc * 4];
          acc[q] = fmaf(xv.x, w4.x, fmaf(xv.y, w4.y, fmaf(xv.z, w4.z, fmaf(xv.w, w4.w, acc[q]))));
        }
      }
#pragma unroll
      for (int q = 0; q < 3; ++q) qx_s[w][q][lane] = acc[q];
      PB();
      // g2[hl*3+q][j] = sum_D PKT[j][D] * q2[q][D]  (float4 packed; SCALE folded)
      {
        float g2[6] = {0, 0, 0, 0, 0, 0};
        const int D0 = half * 32;
        const float* pkt = &ws[PKT2F + j32 * 64 + D0];
#pragma unroll
        for (int dd = 0; dd < 8; ++dd) {
          const float4 wk4 = *(const float4*)&pkt[dd * 4];
          const int hl = dd >> 2;
#pragma unroll
          for (int q = 0; q < 3; ++q) {
            const float4 q4 = *(const float4*)&qx_s[w][q][D0 + dd * 4];
            g2[hl * 3 + q] = fmaf(q4.x, wk4.x, fmaf(q4.y, wk4.y,
                              fmaf(q4.z, wk4.z, fmaf(q4.w, wk4.w, g2[hl * 3 + q]))));
          }
        }
#pragma unroll
        for (int k = 0; k < 6; ++k) ch_s[w][hq0 + k][j32] = g2[k];
      }
      PB();
    }

    // scores: lane=(t,q), s[h] = sum_j a[t][j] * g[h*3+q][j]
    const float (*g)[36] = (l == 0) ? (const float (*)[36])g1_s : (const float (*)[36])ch_s[w];
    if (lane < 60) {
      float acc[4] = {0, 0, 0, 0};
#pragma unroll
      for (int jc = 0; jc < 8; ++jc) {
        const float4 av = *(const float4*)&a_s[w][t3][jc * 4];
#pragma unroll
        for (int h = 0; h < 4; ++h) {
          const float4 gv = *(const float4*)&g[h * 3 + q3][jc * 4];
          acc[h] = fmaf(av.x, gv.x, fmaf(av.y, gv.y, fmaf(av.z, gv.z, fmaf(av.w, gv.w, acc[h]))));
        }
      }
#pragma unroll
      for (int h = 0; h < 4; ++h) att_s[w][h * 3 + q3][t3] = acc[h];
    }
    PB();

    // wave-parallel softmax: 4 lanes/row x 5 t each; quad-reduce on DPP (VALU)
    if (r12 < 12) {
      const int tb = sub * 5;
      float v0 = att_s[w][r12][tb],     v1 = att_s[w][r12][tb + 1];
      float v2 = att_s[w][r12][tb + 2], v3 = att_s[w][r12][tb + 3];
      float v4 = att_s[w][r12][tb + 4];
      float m = fmaxf(fmaxf(fmaxf(v0, v1), fmaxf(v2, v3)), v4);
      m = dppmax<0xB1>(m);
      m = dppmax<0x4E>(m);
      v0 = exp2f(v0 - m); v1 = exp2f(v1 - m); v2 = exp2f(v2 - m);
      v3 = exp2f(v3 - m); v4 = exp2f(v4 - m);
      float s = v0 + v1 + v2 + v3 + v4;
      s = dppadd<0xB1>(s);
      s = dppadd<0x4E>(s);
      const float inv = 1.f / s;
      att_s[w][r12][tb]     = v0 * inv;
      att_s[w][r12][tb + 1] = v1 * inv;
      att_s[w][r12][tb + 2] = v2 * inv;
      att_s[w][r12][tb + 3] = v3 * inv;
      att_s[w][r12][tb + 4] = v4 * inv;
    }
    PB();

    // ch[hq][j] = sum_t att[hq][t] * a[t][j]  (att pre-normalized)
    {
      float c[6] = {0, 0, 0, 0, 0, 0};
#pragma unroll
      for (int tc = 0; tc < 5; ++tc) {
        float av[4];
#pragma unroll
        for (int r = 0; r < 4; ++r) av[r] = a_s[w][tc * 4 + r][j32];
#pragma unroll
        for (int k = 0; k < 6; ++k) {
          const float4 at = *(const float4*)&att_s[w][hq0 + k][tc * 4];
          c[k] = fmaf(at.x, av[0], fmaf(at.y, av[1], fmaf(at.z, av[2], fmaf(at.w, av[3], c[k]))));
        }
      }
#pragma unroll
      for (int k = 0; k < 6; ++k) ch_s[w][hq0 + k][j32] = c[k];
    }
    PB();

    // o[q][d] = sum_j ch[h(d)*3+q][j] * Wvf[j][d] + bvf[d]  (packed Wv)
    {
      const int pv = l ? PV2 : PV1;
      const float bv = ws[(l ? BVF2F : BVF1F) + lane];
      float o[3] = {bv, bv, bv};
#pragma unroll
      for (int jc = 0; jc < 8; ++jc) {
        const float4 w4 = *(const float4*)&ws[pv + jc * 256 + lane * 4];
#pragma unroll
        for (int q = 0; q < 3; ++q) {
          const float4 cv = *(const float4*)&ch_s[w][h16 * 3 + q][jc * 4];
          o[q] = fmaf(cv.x, w4.x, fmaf(cv.y, w4.y, fmaf(cv.z, w4.z, fmaf(cv.w, w4.w, o[q]))));
        }
      }
#pragma unroll
      for (int q = 0; q < 3; ++q) qx_s[w][q][lane] = o[q];
    }
    PB();

    // O-proj + residual + LN  (packed wo; merged-moment DPP reduction)
    {
      const int po = l ? PO2 : PO1;
      const float* bo = l ? p.bo2 : p.bo1;
      const float* gg = l ? p.n2_g : p.n1_g;
      const float* gb = l ? p.n2_b : p.n1_b;
      float acc[3];
#pragma unroll
      for (int q = 0; q < 3; ++q)
        acc[q] = bo[lane] + (l ? xq[q] : p.qemb[q * 64 + lane]);
#pragma unroll
      for (int jc = 0; jc < 16; ++jc) {
        const float4 w4 = *(const float4*)&ws[po + jc * 256 + lane * 4];
#pragma unroll
        for (int q = 0; q < 3; ++q) {
          const float4 ov = *(const float4*)&qx_s[w][q][jc * 4];
          acc[q] = fmaf(ov.x, w4.x, fmaf(ov.y, w4.y, fmaf(ov.z, w4.z, fmaf(ov.w, w4.w, acc[q]))));
        }
      }
      const float gv = gg[lane], bv = gb[lane];
#pragma unroll
      for (int q = 0; q < 3; ++q) {
        const float v = acc[q];
        const float s = wsum64(v);
        const float s2 = wsum64(v * v);
        const float mu = s * (1.f / 64.f);
        const float var = fmaf(s2, 1.f / 64.f, -mu * mu);
        const float inv = rsqrtf(var + 1e-5f);
        const float xn = fmaf((v - mu) * inv, gv, bv);
        xq[q] = xn;
        x_s[w][q][lane] = xn;
      }
    }
    PB();
  }

  // FFN1: f1 = relu(x2 @ w1 + b1) -> overlay on a_s
  float* f1p = (float*)a_s[w];
  {
    float a0[3], a1[3];
    const float b0 = p.ffn_b1[lane], b1 = p.ffn_b1[64 + lane];
#pragma unroll
    for (int q = 0; q < 3; ++q) { a0[q] = b0; a1[q] = b1; }
#pragma unroll
    for (int jc = 0; jc < 16; ++jc) {
      const float4 w04 = *(const float4*)&ws[PF1 + jc * 512 + lane * 4];
      const float4 w14 = *(const float4*)&ws[PF1 + jc * 512 + 256 + lane * 4];
#pragma unroll
      for (int q = 0; q < 3; ++q) {
        const float4 xv = *(const float4*)&x_s[w][q][jc * 4];
        a0[q] = fmaf(xv.x, w04.x, fmaf(xv.y, w04.y, fmaf(xv.z, w04.z, fmaf(xv.w, w04.w, a0[q]))));
        a1[q] = fmaf(xv.x, w14.x, fmaf(xv.y, w14.y, fmaf(xv.z, w14.z, fmaf(xv.w, w14.w, a1[q]))));
      }
    }
#pragma unroll
    for (int q = 0; q < 3; ++q) {
      f1p[q * 136 + lane] = fmaxf(a0[q], 0.f);
      f1p[q * 136 + 64 + lane] = fmaxf(a1[q], 0.f);
    }
  }
  PB();

  // FFN2 + residual + LN3
  {
    float acc[3];
#pragma unroll
    for (int q = 0; q < 3; ++q) acc[q] = p.ffn_b2[lane] + xq[q];
#pragma unroll
    for (int mc = 0; mc < 32; ++mc) {
      const float4 w4 = *(const float4*)&ws[PF2 + mc * 256 + lane * 4];
#pragma unroll
      for (int q = 0; q < 3; ++q) {
        const float4 fv = *(const float4*)&f1p[q * 136 + mc * 4];
        acc[q] = fmaf(fv.x, w4.x, fmaf(fv.y, w4.y, fmaf(fv.z, w4.z, fmaf(fv.w, w4.w, acc[q]))));
      }
    }
    const float gv = p.n3_g[lane], bv = p.n3_b[lane];
#pragma unroll
    for (int q = 0; q < 3; ++q) {
      const float v = acc[q];
      const float s = wsum64(v);
      const float s2 = wsum64(v * v);
      const float mu = s * (1.f / 64.f);
      const float var = fmaf(s2, 1.f / 64.f, -mu * mu);
      const float inv = rsqrtf(var + 1e-5f);
      x_s[w][q][lane] = fmaf((v - mu) * inv, gv, bv);
    }
  }
  PB();

  // fused heads: y1 = relu(x3 @ op_w1 + op_b1) in regs (lane<32), then
  // out[q][e] = sum_m y1[q][m]*op_w2[m][e] + op_b2[e] via 32-lane DPP reduce.
  if (lane < 32) {
    float acc[3];
#pragma unroll
    for (int q = 0; q < 3; ++q) acc[q] = p.op_b1[lane];
#pragma unroll
    for (int jc = 0; jc < 16; ++jc) {
      const float4 w4 = *(const float4*)&ws[POP1 + jc * 128 + lane * 4];
#pragma unroll
      for (int q = 0; q < 3; ++q) {
        const float4 xv = *(const float4*)&x_s[w][q][jc * 4];
        acc[q] = fmaf(xv.x, w4.x, fmaf(xv.y, w4.y, fmaf(xv.z, w4.z, fmaf(xv.w, w4.w, acc[q]))));
      }
    }
    const float w0 = p.op_w2[lane * 2 + 0];
    const float w1 = p.op_w2[lane * 2 + 1];
    float r[6];
#pragma unroll
    for (int q = 0; q < 3; ++q) {
      const float y = fmaxf(acc[q], 0.f);
      r[q * 2 + 0] = y * w0;
      r[q * 2 + 1] = y * w1;
    }
#pragma unroll
    for (int k = 0; k < 6; ++k) r[k] = wsum32(r[k]);
    if (lane == 0) {
#pragma unroll
      for (int k = 0; k < 6; ++k)
        p.out[item * 6 + k] = r[k] + p.op_b2[k & 1];
    }
  }
}

extern "C" void kernel_launch(void* const* d_in, const int* in_sizes, int n_in,
                              void* d_out, int out_size, void* d_ws, size_t ws_size,
                              hipStream_t stream) {
  const float* in[40];
  for (int i = 0; i < n_in && i < 40; ++i) in[i] = (const float*)d_in[i];

  const float *a1_wq, *a1_wk, *a1_wv, *a1_wo, *a1_bq, *a1_bk, *a1_bv, *a1_bo;
  const float *a2_wq, *a2_wk, *a2_wv, *a2_wo, *a2_bq, *a2_bk, *a2_bv, *a2_bo;
  if (in_sizes[8] == 4096) {
    a1_wq = in[7];  a1_wk = in[8];  a1_wv = in[9];  a1_wo = in[10];
    a1_bq = in[11]; a1_bk = in[12]; a1_bv = in[13]; a1_bo = in[14];
    a2_wq = in[15]; a2_wk = in[16]; a2_wv = in[17]; a2_wo = in[18];
    a2_bq = in[19]; a2_bk = in[20]; a2_bv = in[21]; a2_bo = in[22];
  } else {
    a1_wq = in[7];  a1_bq = in[8];  a1_wk = in[9];  a1_bk = in[10];
    a1_wv = in[11]; a1_bv = in[12]; a1_wo = in[13]; a1_bo = in[14];
    a2_wq = in[15]; a2_bq = in[16]; a2_wk = in[17]; a2_bk = in[18];
    a2_wv = in[19]; a2_bv = in[20]; a2_wo = in[21]; a2_bo = in[22];
  }
  (void)a1_bk; (void)a2_bk;  // K biases fold out of softmax exactly

  float* ws = (float*)d_ws;
  prep12_kernel<<<26, 384, 0, stream>>>(in[5], in[6], a1_wk, a2_wk, a1_wv, a2_wv,
                                        a1_bv, a2_bv, in[2], a1_wq, a1_bq, ws);
  prepC_kernel<<<136, 256, 0, stream>>>(ws, a2_wq, a1_wo, a2_wo, in[23], in[25], in[33]);

  Params p;
  p.tl = in[0]; p.tr = in[1]; p.qemb = in[2];
  p.ip_w1 = in[3]; p.ip_b1 = in[4];
  p.bq2 = a2_bq;
  p.bo1 = a1_bo; p.bo2 = a2_bo;
  p.ffn_b1 = in[24]; p.ffn_b2 = in[26];
  p.n1_g = in[27]; p.n1_b = in[28]; p.n2_g = in[29]; p.n2_b = in[30];
  p.n3_g = in[31]; p.n3_b = in[32];
  p.op_b1 = in[34]; p.op_w2 = in[35]; p.op_b2 = in[36];
  p.ws = ws; p.out = (float*)d_out;

  planner_kernel<<<8192, 256, 0, stream>>>(p);
}